// Round 16
// baseline (516.851 us; speedup 1.0000x reference)
//
#include <hip/hip_runtime.h>

#define NNODES 50000
#define NEDGES 800000
#define SCAN_BLOCKS ((NNODES + 255) / 256)   // 196
#define NPART (NNODES / 8)                   // 6250 nodes per XCD partition
#define EPS 2048                             // edges per slice
#define NSLICE ((NEDGES + EPS - 1) / EPS)    // 391

typedef unsigned short u16;

// per-edge attention weights: softmax over heads of (s_src - s_dst + c)
__device__ __forceinline__ float4 softq(float4 ss, float4 sd, float4 c4) {
  float l0 = ss.x - sd.x + c4.x;
  float l1 = ss.y - sd.y + c4.y;
  float l2 = ss.z - sd.z + c4.z;
  float l3 = ss.w - sd.w + c4.w;
  float mx = fmaxf(fmaxf(l0, l1), fmaxf(l2, l3));
  float e0 = __expf(l0 - mx), e1 = __expf(l1 - mx);
  float e2 = __expf(l2 - mx), e3 = __expf(l3 - mx);
  float inv = 1.f / (e0 + e1 + e2 + e3);
  return make_float4(e0 * inv, e1 * inv, e2 * inv, e3 * inv);
}

__device__ __forceinline__ void fma4(float4& a, float q, float4 v) {
  a.x += q * v.x; a.y += q * v.y; a.z += q * v.z; a.w += q * v.w;
}
__device__ __forceinline__ float dot4(float4 a, float4 b) {
  return a.x * b.x + a.y * b.y + a.z * b.z + a.w * b.w;
}
__device__ __forceinline__ void st4T(float* ldsT, int k0, int NBp, int nl, float4 v) {
  ldsT[(k0 + 0) * NBp + nl] = v.x;
  ldsT[(k0 + 1) * NBp + nl] = v.y;
  ldsT[(k0 + 2) * NBp + nl] = v.z;
  ldsT[(k0 + 3) * NBp + nl] = v.w;
}
__device__ __forceinline__ float4 shfl4(float4 v, int e, int w) {
  return make_float4(__shfl(v.x, e, w), __shfl(v.y, e, w),
                     __shfl(v.z, e, w), __shfl(v.w, e, w));
}

// ---------------- CSR build: histogram over dst + per-edge rank (u16) --------
__global__ __launch_bounds__(256) void hist_kernel(const int* __restrict__ ei,
                                                   int* __restrict__ counts,
                                                   u16* __restrict__ rank) {
  int e = blockIdx.x * 256 + threadIdx.x;
  if (e < NEDGES) rank[e] = (u16)atomicAdd(&counts[ei[NEDGES + e]], 1);
}

__global__ __launch_bounds__(256) void scanA_kernel(const int* __restrict__ counts,
                                                    int* __restrict__ rowptr,
                                                    int* __restrict__ blockSum) {
  __shared__ int sm[256];
  int i = blockIdx.x * 256 + threadIdx.x;
  int v = (i < NNODES) ? counts[i] : 0;
  sm[threadIdx.x] = v;
  __syncthreads();
  for (int off = 1; off < 256; off <<= 1) {
    int x = (threadIdx.x >= off) ? sm[threadIdx.x - off] : 0;
    __syncthreads();
    sm[threadIdx.x] += x;
    __syncthreads();
  }
  if (i < NNODES) rowptr[i] = sm[threadIdx.x] - v;
  if (threadIdx.x == 255) blockSum[blockIdx.x] = sm[255];
}

// merged scanB+scanC: every block redundantly scans the 196 block sums in LDS,
// then applies its exclusive offset to its rowptr slice.
__global__ __launch_bounds__(256) void scanBC_kernel(const int* __restrict__ blockSum,
                                                     int* __restrict__ rowptr) {
  __shared__ int sm[256];
  int v = (threadIdx.x < SCAN_BLOCKS) ? blockSum[threadIdx.x] : 0;
  sm[threadIdx.x] = v;
  __syncthreads();
  for (int off = 1; off < 256; off <<= 1) {
    int x = (threadIdx.x >= off) ? sm[threadIdx.x - off] : 0;
    __syncthreads();
    sm[threadIdx.x] += x;
    __syncthreads();
  }
  int off = (blockIdx.x == 0) ? 0 : sm[blockIdx.x - 1];  // exclusive prefix
  int i = blockIdx.x * 256 + threadIdx.x;
  if (i < NNODES) rowptr[i] += off;
  if (i == 0) rowptr[NNODES] = NEDGES;
}

// Atomic-free XCD-partitioned scatter; u16 col halves writeback amplification.
__global__ __launch_bounds__(256) void scatter_kernel(const int* __restrict__ ei,
                                                      const int* __restrict__ rowptr,
                                                      const u16* __restrict__ rank,
                                                      u16* __restrict__ col) {
  const int p = blockIdx.x & 7;
  const int sl = blockIdx.x >> 3;
  const int P0 = p * NPART;
  const int e1 = min((sl + 1) * EPS, NEDGES);
  for (int e = sl * EPS + threadIdx.x; e < e1; e += 256) {
    int dst = __builtin_nontemporal_load(&ei[NEDGES + e]);
    if ((unsigned)(dst - P0) < (unsigned)NPART) {
      int pos = rowptr[dst] + (int)__builtin_nontemporal_load(&rank[e]);
      col[pos] = (u16)__builtin_nontemporal_load(&ei[e]);
    }
  }
}

// ---------------- W pre-transpose into [k][o] rows (scalar-load friendly) ----
__global__ __launch_bounds__(256) void prep_kernel(const float* __restrict__ W1,
                                                   const float* __restrict__ W2,
                                                   const float* __restrict__ W3,
                                                   float* __restrict__ Wk1,
                                                   float* __restrict__ Wk2,
                                                   float* __restrict__ Wk3) {
  int i = blockIdx.x * 256 + threadIdx.x;
  if (i < 4096) {
    int f = i >> 6, j = i & 63;
    Wk1[i] = W1[f * 64 + ((j & 3) << 4) + (j >> 2)];
  } else if (i < 6144) {
    int i2 = i - 4096;
    int k = i2 >> 5, o = i2 & 31;
    int hh = k >> 4, f = k & 15;
    Wk2[i2] = W2[f * 128 + hh * 32 + o];
  } else if (i < 14336) {
    int i3 = i - 6144;
    int k = i3 >> 6, o = i3 & 63;
    int hh = k >> 5, f = k & 31;
    Wk3[i3] = W3[f * 256 + hh * 64 + o];
  }
}

// ---------------- layer-1 t GEMM: t[n][j] = x[n][:64] . Wk1[j][:64] ----------
template<int K, int OUTT, int MO>
__global__ __launch_bounds__(256) void ngemm_kernel(const float* __restrict__ A,
                                                    const float* __restrict__ Wk,
                                                    float* __restrict__ C) {
  constexpr int OG = OUTT / MO;
  constexpr int NB = 256 / OG;
  constexpr int NBp = NB + 1;
  __shared__ float ldsT[K * NBp];
  const int tid = threadIdx.x;
  const int nb0 = blockIdx.x * NB;
  for (int i = tid; i < NB * (K / 4); i += 256) {
    int r = i / (K / 4), kq = i - r * (K / 4);
    int n = nb0 + r;
    if (n >= NNODES) n = NNODES - 1;
    float4 v = ((const float4*)A)[n * (K / 4) + kq];
    st4T(ldsT, kq << 2, NBp, r, v);
  }
  __syncthreads();
  const int o0 = __builtin_amdgcn_readfirstlane(tid / NB) * MO;
  const int nl = tid & (NB - 1);
  const int n = nb0 + nl;
  float acc[MO];
#pragma unroll
  for (int m = 0; m < MO; ++m) acc[m] = 0.f;
#pragma unroll 4
  for (int k = 0; k < K; ++k) {
    float a = ldsT[k * NBp + nl];
    const float* wr = Wk + k * OUTT + o0;   // wave-uniform -> s_load
#pragma unroll
    for (int m = 0; m < MO; ++m) acc[m] += a * wr[m];
  }
  if (n < NNODES) {
#pragma unroll
    for (int m4 = 0; m4 < MO / 4; ++m4) {
      float4 v = make_float4(acc[m4 * 4 + 0], acc[m4 * 4 + 1],
                             acc[m4 * 4 + 2], acc[m4 * 4 + 3]);
      ((float4*)C)[n * (OUTT / 4) + (o0 >> 2) + m4] = v;
    }
  }
}

// ---------------- fused g-gather + transform (layers 2/3) ----------------
// Phase 1: gather with fused softmax (lane-split + shfl broadcast), results
// written straight into the transposed LDS tile. Phase 2: ngemm loop, /deg+
// bias+relu epilogue. STATS: wave-level shfl reduce of BN sums (o0 is
// wave-uniform) + one atomic per channel per wave.
template<int FIN, int OUTT, int MO, bool STATS>
__global__ __launch_bounds__(256) void fusedG_kernel(const int* __restrict__ rowptr,
                                                     const u16* __restrict__ col,
                                                     const float* __restrict__ s,
                                                     const float* __restrict__ x,
                                                     const float* __restrict__ Wk,
                                                     const float* __restrict__ cptr,
                                                     const float* __restrict__ bptr,
                                                     float* __restrict__ h,
                                                     float* __restrict__ sums) {
  constexpr int LPN = FIN / 8;        // lanes per node (2 or 4)
  constexpr int NB = 256 / LPN;       // nodes per block (128 or 64)
  constexpr int NBp = NB + 1;
  constexpr int K = 4 * FIN;
  constexpr int OG = OUTT / MO;       // must equal 256/NB (wave-uniform o0)
  static_assert(OG == 256 / NB, "geometry mismatch");
  __shared__ float ldsT[K * NBp];
  const int tid = threadIdx.x;
  const int nb0 = blockIdx.x * NB;
  const float4* sF4 = (const float4*)s;
  const float4* xF4 = (const float4*)x;

  // ---- phase 1: gather ----
  {
    const int lane = tid & (LPN - 1);
    const int sub = tid / LPN;
    int n = nb0 + sub;
    if (n >= NNODES) n = NNODES - 1;   // duplicate work, discarded in phase 2
    float4 c4 = *(const float4*)cptr;
    float mxc = fmaxf(fmaxf(c4.x, c4.y), fmaxf(c4.z, c4.w));
    float4 qsl = make_float4(__expf(c4.x - mxc), __expf(c4.y - mxc),
                             __expf(c4.z - mxc), __expf(c4.w - mxc));
    float sinv = 1.f / (qsl.x + qsl.y + qsl.z + qsl.w);
    qsl.x *= sinv; qsl.y *= sinv; qsl.z *= sinv; qsl.w *= sinv;
    float4 sd = sF4[n];
    const float4* xn = xF4 + n * (FIN / 4) + 2 * lane;
    float4 xa = xn[0], xb = xn[1];
    float4 g0a = make_float4(qsl.x * xa.x, qsl.x * xa.y, qsl.x * xa.z, qsl.x * xa.w);
    float4 g0b = make_float4(qsl.x * xb.x, qsl.x * xb.y, qsl.x * xb.z, qsl.x * xb.w);
    float4 g1a = make_float4(qsl.y * xa.x, qsl.y * xa.y, qsl.y * xa.z, qsl.y * xa.w);
    float4 g1b = make_float4(qsl.y * xb.x, qsl.y * xb.y, qsl.y * xb.z, qsl.y * xb.w);
    float4 g2a = make_float4(qsl.z * xa.x, qsl.z * xa.y, qsl.z * xa.z, qsl.z * xa.w);
    float4 g2b = make_float4(qsl.z * xb.x, qsl.z * xb.y, qsl.z * xb.z, qsl.z * xb.w);
    float4 g3a = make_float4(qsl.w * xa.x, qsl.w * xa.y, qsl.w * xa.z, qsl.w * xa.w);
    float4 g3b = make_float4(qsl.w * xb.x, qsl.w * xb.y, qsl.w * xb.z, qsl.w * xb.w);
    const int beg = rowptr[n], end = rowptr[n + 1];
    int idx = beg;
    for (; idx + LPN <= end; idx += LPN) {
      int myS = (int)col[idx + lane];             // per-lane coalesced
      float4 qL = softq(sF4[myS], sd, c4);        // one softmax per lane
#pragma unroll
      for (int e = 0; e < LPN; ++e) {
        int srcE = __shfl(myS, e, LPN);
        float4 q = shfl4(qL, e, LPN);
        const float4* xr = xF4 + srcE * (FIN / 4) + 2 * lane;
        float4 x0a = xr[0], x0b = xr[1];
        fma4(g0a, q.x, x0a); fma4(g0b, q.x, x0b);
        fma4(g1a, q.y, x0a); fma4(g1b, q.y, x0b);
        fma4(g2a, q.z, x0a); fma4(g2b, q.z, x0b);
        fma4(g3a, q.w, x0a); fma4(g3b, q.w, x0b);
      }
    }
    for (; idx < end; ++idx) {
      int s0 = (int)col[idx];
      float4 qv = softq(sF4[s0], sd, c4);
      const float4* xr = xF4 + s0 * (FIN / 4) + 2 * lane;
      float4 x0a = xr[0], x0b = xr[1];
      fma4(g0a, qv.x, x0a); fma4(g0b, qv.x, x0b);
      fma4(g1a, qv.y, x0a); fma4(g1b, qv.y, x0b);
      fma4(g2a, qv.z, x0a); fma4(g2b, qv.z, x0b);
      fma4(g3a, qv.w, x0a); fma4(g3b, qv.w, x0b);
    }
    const int f0 = 8 * lane;
    st4T(ldsT, 0 * FIN + f0, NBp, sub, g0a); st4T(ldsT, 0 * FIN + f0 + 4, NBp, sub, g0b);
    st4T(ldsT, 1 * FIN + f0, NBp, sub, g1a); st4T(ldsT, 1 * FIN + f0 + 4, NBp, sub, g1b);
    st4T(ldsT, 2 * FIN + f0, NBp, sub, g2a); st4T(ldsT, 2 * FIN + f0 + 4, NBp, sub, g2b);
    st4T(ldsT, 3 * FIN + f0, NBp, sub, g3a); st4T(ldsT, 3 * FIN + f0 + 4, NBp, sub, g3b);
  }
  __syncthreads();

  // ---- phase 2: transform ----
  const int o0 = __builtin_amdgcn_readfirstlane(tid / NB) * MO;
  const int nl = tid & (NB - 1);
  const int n = nb0 + nl;
  float acc[MO];
#pragma unroll
  for (int m = 0; m < MO; ++m) acc[m] = 0.f;
#pragma unroll 4
  for (int k = 0; k < K; ++k) {
    float a = ldsT[k * NBp + nl];
    const float* wr = Wk + k * OUTT + o0;   // wave-uniform -> s_load
#pragma unroll
    for (int m = 0; m < MO; ++m) acc[m] += a * wr[m];
  }
  float sS[MO], sQ[MO];
#pragma unroll
  for (int m = 0; m < MO; ++m) { sS[m] = 0.f; sQ[m] = 0.f; }
  if (n < NNODES) {
    float sc = 1.f / (float)(rowptr[n + 1] - rowptr[n] + 1);
#pragma unroll
    for (int m4 = 0; m4 < MO / 4; ++m4) {
      float4 v;
      v.x = fmaxf(acc[m4 * 4 + 0] * sc + bptr[o0 + m4 * 4 + 0], 0.f);
      v.y = fmaxf(acc[m4 * 4 + 1] * sc + bptr[o0 + m4 * 4 + 1], 0.f);
      v.z = fmaxf(acc[m4 * 4 + 2] * sc + bptr[o0 + m4 * 4 + 2], 0.f);
      v.w = fmaxf(acc[m4 * 4 + 3] * sc + bptr[o0 + m4 * 4 + 3], 0.f);
      ((float4*)h)[n * (OUTT / 4) + (o0 >> 2) + m4] = v;
      if (STATS) {
        sS[m4 * 4 + 0] = v.x; sQ[m4 * 4 + 0] = v.x * v.x;
        sS[m4 * 4 + 1] = v.y; sQ[m4 * 4 + 1] = v.y * v.y;
        sS[m4 * 4 + 2] = v.z; sQ[m4 * 4 + 2] = v.z * v.z;
        sS[m4 * 4 + 3] = v.w; sQ[m4 * 4 + 3] = v.w * v.w;
      }
    }
  }
  if (STATS) {
#pragma unroll
    for (int m = 0; m < MO; ++m) {
      float a = sS[m], q = sQ[m];
#pragma unroll
      for (int off = 1; off < 64; off <<= 1) {
        a += __shfl_xor(a, off);
        q += __shfl_xor(q, off);
      }
      if ((tid & 63) == 0) {
        atomicAdd(&sums[o0 + m], a);
        atomicAdd(&sums[64 + o0 + m], q);
      }
    }
  }
}

// ---------------- s = x @ u  ([N,4]) ----------------
template<int FIN>
__global__ __launch_bounds__(256) void s_kernel(const float* __restrict__ x,
                                                const float* __restrict__ u,
                                                float* __restrict__ s) {
  int tid = blockIdx.x * 256 + threadIdx.x;
  int n = tid >> 2, h = tid & 3;
  if (n >= NNODES) return;
  const float4* xr = (const float4*)x + n * (FIN / 4);
  float acc = 0.f;
#pragma unroll
  for (int f4 = 0; f4 < FIN / 4; ++f4) {
    float4 xv = xr[f4];
    acc += xv.x * u[(4 * f4 + 0) * 4 + h] + xv.y * u[(4 * f4 + 1) * 4 + h] +
           xv.z * u[(4 * f4 + 2) * 4 + h] + xv.w * u[(4 * f4 + 3) * 4 + h];
  }
  s[tid] = acc;  // tid == n*4+h
}

// ---------------- layer-1 gather over t, fused softmax + shfl dedup ----------
__global__ __launch_bounds__(256) void gather1_kernel(const int* __restrict__ rowptr,
                                                      const u16* __restrict__ col,
                                                      const float* __restrict__ s,
                                                      const float* __restrict__ t,
                                                      const float* __restrict__ cptr,
                                                      const float* __restrict__ bptr,
                                                      float* __restrict__ h) {
  const int lane = threadIdx.x & 7;
  const int sub = threadIdx.x >> 3;
  const int n = blockIdx.x * 32 + sub;
  if (n >= NNODES) return;
  const float4* sF4 = (const float4*)s;
  const float4* tF4 = (const float4*)t;
  float4 c4 = *(const float4*)cptr;
  float mxc = fmaxf(fmaxf(c4.x, c4.y), fmaxf(c4.z, c4.w));
  float4 qs = make_float4(__expf(c4.x - mxc), __expf(c4.y - mxc),
                          __expf(c4.z - mxc), __expf(c4.w - mxc));
  float sinv = 1.f / (qs.x + qs.y + qs.z + qs.w);
  qs.x *= sinv; qs.y *= sinv; qs.z *= sinv; qs.w *= sinv;
  float4 sd = sF4[n];
  const float4* trow = tF4 + n * 16 + 2 * lane;
  float acc0 = dot4(qs, trow[0]);
  float acc1 = dot4(qs, trow[1]);
  const int beg = rowptr[n], end = rowptr[n + 1];
  int idx = beg;
  for (; idx + 8 <= end; idx += 8) {
    int myS = (int)col[idx + lane];            // per-lane coalesced
    float4 qL = softq(sF4[myS], sd, c4);       // one softmax per lane
#pragma unroll
    for (int e = 0; e < 8; ++e) {
      int srcE = __shfl(myS, e, 8);
      float4 q = shfl4(qL, e, 8);
      const float4* tw = tF4 + srcE * 16 + 2 * lane;
      acc0 += dot4(q, tw[0]);
      acc1 += dot4(q, tw[1]);
    }
  }
  for (; idx < end; ++idx) {
    int src = (int)col[idx];
    float4 qv = softq(sF4[src], sd, c4);
    const float4* tw = tF4 + src * 16 + 2 * lane;
    acc0 += dot4(qv, tw[0]);
    acc1 += dot4(qv, tw[1]);
  }
  float d = 1.f / (float)(end - beg + 1);
  h[n * 16 + 2 * lane + 0] = fmaxf(acc0 * d + bptr[2 * lane + 0], 0.f);
  h[n * 16 + 2 * lane + 1] = fmaxf(acc1 * d + bptr[2 * lane + 1], 0.f);
}

// ---------------- BN + MLP head + sigmoid, one thread per node ----------------
__global__ __launch_bounds__(256) void mlp_kernel(
    const float* __restrict__ h3, const float* __restrict__ sums,
    const float* __restrict__ gamma, const float* __restrict__ beta,
    const float* __restrict__ lw1, const float* __restrict__ lb1,
    const float* __restrict__ lw2, const float* __restrict__ lb2,
    const float* __restrict__ lw3, const float* __restrict__ lb3,
    const float* __restrict__ lw4, const float* __restrict__ lb4,
    const float* __restrict__ ow, const float* __restrict__ ob,
    float* __restrict__ out) {
  __shared__ float w1[64 * 32], w2[32 * 16], w3[16 * 8], w4[8 * 4];
  __shared__ float b1s[32], b2s[16], b3s[8], b4s[4], wos[4];
  __shared__ float scale[64], shift[64];
  int tid = threadIdx.x;
  for (int i = tid; i < 64 * 32; i += 256) w1[i] = lw1[i];
  for (int i = tid; i < 32 * 16; i += 256) w2[i] = lw2[i];
  if (tid < 128) w3[tid] = lw3[tid];
  if (tid < 32) { w4[tid] = lw4[tid]; b1s[tid] = lb1[tid]; }
  if (tid < 16) b2s[tid] = lb2[tid];
  if (tid < 8) b3s[tid] = lb3[tid];
  if (tid < 4) { b4s[tid] = lb4[tid]; wos[tid] = ow[tid]; }
  if (tid < 64) {
    float mu = sums[tid] * (1.f / NNODES);
    float var = sums[64 + tid] * (1.f / NNODES) - mu * mu;
    float sc = rsqrtf(var + 1e-5f) * gamma[tid];
    scale[tid] = sc;
    shift[tid] = beta[tid] - mu * sc;
  }
  __syncthreads();
  int n = blockIdx.x * 256 + tid;
  if (n >= NNODES) return;
  float obv = ob[0];
  const float4* hr = (const float4*)h3 + n * 16;
  float z1[32];
#pragma unroll
  for (int j = 0; j < 32; ++j) z1[j] = b1s[j];
  for (int i4 = 0; i4 < 16; ++i4) {
    float4 hv = hr[i4];
    float a0 = hv.x * scale[4 * i4 + 0] + shift[4 * i4 + 0];
    float a1 = hv.y * scale[4 * i4 + 1] + shift[4 * i4 + 1];
    float a2 = hv.z * scale[4 * i4 + 2] + shift[4 * i4 + 2];
    float a3 = hv.w * scale[4 * i4 + 3] + shift[4 * i4 + 3];
#pragma unroll
    for (int j = 0; j < 32; ++j) {
      z1[j] += a0 * w1[(4 * i4 + 0) * 32 + j] + a1 * w1[(4 * i4 + 1) * 32 + j] +
               a2 * w1[(4 * i4 + 2) * 32 + j] + a3 * w1[(4 * i4 + 3) * 32 + j];
    }
  }
  float z2[16];
#pragma unroll
  for (int j = 0; j < 16; ++j) z2[j] = b2s[j];
  for (int i = 0; i < 32; ++i) {
    float a = fmaxf(z1[i], 0.f);
#pragma unroll
    for (int j = 0; j < 16; ++j) z2[j] += a * w2[i * 16 + j];
  }
  float z3[8];
#pragma unroll
  for (int j = 0; j < 8; ++j) z3[j] = b3s[j];
  for (int i = 0; i < 16; ++i) {
    float a = fmaxf(z2[i], 0.f);
#pragma unroll
    for (int j = 0; j < 8; ++j) z3[j] += a * w3[i * 8 + j];
  }
  float z4[4];
#pragma unroll
  for (int j = 0; j < 4; ++j) z4[j] = b4s[j];
  for (int i = 0; i < 8; ++i) {
    float a = fmaxf(z3[i], 0.f);
#pragma unroll
    for (int j = 0; j < 4; ++j) z4[j] += a * w4[i * 4 + j];
  }
  float zo = obv;
#pragma unroll
  for (int i = 0; i < 4; ++i) zo += fmaxf(z4[i], 0.f) * wos[i];
  out[n] = 1.f / (1.f + __expf(-zo));
}

extern "C" void kernel_launch(void* const* d_in, const int* in_sizes, int n_in,
                              void* d_out, int out_size, void* d_ws, size_t ws_size,
                              hipStream_t stream) {
  const float* x  = (const float*)d_in[0];
  const int*   ei = (const int*)d_in[1];
  const float* W1 = (const float*)d_in[2];  const float* u1 = (const float*)d_in[3];
  const float* c1 = (const float*)d_in[4];  const float* b1 = (const float*)d_in[5];
  const float* W2 = (const float*)d_in[6];  const float* u2 = (const float*)d_in[7];
  const float* c2 = (const float*)d_in[8];  const float* b2 = (const float*)d_in[9];
  const float* W3 = (const float*)d_in[10]; const float* u3 = (const float*)d_in[11];
  const float* c3 = (const float*)d_in[12]; const float* b3 = (const float*)d_in[13];
  const float* gamma = (const float*)d_in[14]; const float* beta = (const float*)d_in[15];
  const float* lw1 = (const float*)d_in[16]; const float* lb1 = (const float*)d_in[17];
  const float* lw2 = (const float*)d_in[18]; const float* lb2 = (const float*)d_in[19];
  const float* lw3 = (const float*)d_in[20]; const float* lb3 = (const float*)d_in[21];
  const float* lw4 = (const float*)d_in[22]; const float* lb4 = (const float*)d_in[23];
  const float* ow  = (const float*)d_in[24]; const float* ob  = (const float*)d_in[25];
  float* out = (float*)d_out;

  float* t    = (float*)d_ws;                         // N*64   (layer-1 t)
  float* hA   = t + (size_t)NNODES * 64;              // N*64
  float* hB   = hA + (size_t)NNODES * 64;             // N*64
  float* s    = hB + (size_t)NNODES * 64;             // N*4
  float* sums = s + (size_t)NNODES * 4;               // 128
  float* Wk1  = sums + 128;                           // 4096
  float* Wk2  = Wk1 + 4096;                           // 2048
  float* Wk3  = Wk2 + 2048;                           // 8192
  int*   rowptr   = (int*)(Wk3 + 8192);               // N+1 (pad 8)
  int*   counts   = rowptr + NNODES + 8;              // N
  int*   blockSum = counts + NNODES;                  // 256
  u16*   col      = (u16*)(blockSum + 256);           // E u16
  u16*   rank     = col + NEDGES;                     // E u16

  hipMemsetAsync(counts, 0, NNODES * sizeof(int), stream);
  hipMemsetAsync(sums, 0, 128 * sizeof(float), stream);

  // ---- W transposes + CSR by dst ----
  prep_kernel<<<56, 256, 0, stream>>>(W1, W2, W3, Wk1, Wk2, Wk3);
  hist_kernel<<<(NEDGES + 255) / 256, 256, 0, stream>>>(ei, counts, rank);
  scanA_kernel<<<SCAN_BLOCKS, 256, 0, stream>>>(counts, rowptr, blockSum);
  scanBC_kernel<<<SCAN_BLOCKS, 256, 0, stream>>>(blockSum, rowptr);
  scatter_kernel<<<NSLICE * 8, 256, 0, stream>>>(ei, rowptr, rank, col);

  // ---- layer 1: 64 -> 16 (t-gather, fused softmax) ----
  ngemm_kernel<64, 64, 16><<<(NNODES + 63) / 64, 256, 0, stream>>>(x, Wk1, t);
  s_kernel<64><<<(NNODES * 4 + 255) / 256, 256, 0, stream>>>(x, u1, s);
  gather1_kernel<<<(NNODES + 31) / 32, 256, 0, stream>>>(rowptr, col, s, t, c1, b1, hA);

  // ---- layer 2: 16 -> 32 (fused gather+transform) ----
  s_kernel<16><<<(NNODES * 4 + 255) / 256, 256, 0, stream>>>(hA, u2, s);
  fusedG_kernel<16, 32, 16, false><<<(NNODES + 127) / 128, 256, 0, stream>>>(
      rowptr, col, s, hA, Wk2, c2, b2, hB, nullptr);

  // ---- layer 3: 32 -> 64 (fused gather+transform + BN stats) ----
  s_kernel<32><<<(NNODES * 4 + 255) / 256, 256, 0, stream>>>(hB, u3, s);
  fusedG_kernel<32, 64, 16, true><<<(NNODES + 63) / 64, 256, 0, stream>>>(
      rowptr, col, s, hB, Wk3, c3, b3, hA, sums);

  // ---- BN + MLP head ----
  mlp_kernel<<<(NNODES + 255) / 256, 256, 0, stream>>>(hA, sums, gamma, beta, lw1, lb1,
                                                       lw2, lb2, lw3, lb3, lw4, lb4,
                                                       ow, ob, out);
}

// Round 17
// 241.485 us; speedup vs baseline: 2.1403x; 2.1403x over previous
//
#include <hip/hip_runtime.h>

#define NNODES 50000
#define NEDGES 800000
#define SCAN_BLOCKS ((NNODES + 255) / 256)   // 196
#define NPART (NNODES / 8)                   // 6250 nodes per XCD partition
#define EPS 2048                             // edges per slice
#define NSLICE ((NEDGES + EPS - 1) / EPS)    // 391

// per-edge attention weights: softmax over heads of (s_src - s_dst + c)
__device__ __forceinline__ float4 softq(float4 ss, float4 sd, float4 c4) {
  float l0 = ss.x - sd.x + c4.x;
  float l1 = ss.y - sd.y + c4.y;
  float l2 = ss.z - sd.z + c4.z;
  float l3 = ss.w - sd.w + c4.w;
  float mx = fmaxf(fmaxf(l0, l1), fmaxf(l2, l3));
  float e0 = __expf(l0 - mx), e1 = __expf(l1 - mx);
  float e2 = __expf(l2 - mx), e3 = __expf(l3 - mx);
  float inv = 1.f / (e0 + e1 + e2 + e3);
  return make_float4(e0 * inv, e1 * inv, e2 * inv, e3 * inv);
}

__device__ __forceinline__ void fma4(float4& a, float q, float4 v) {
  a.x += q * v.x; a.y += q * v.y; a.z += q * v.z; a.w += q * v.w;
}
__device__ __forceinline__ float dot4(float4 a, float4 b) {
  return a.x * b.x + a.y * b.y + a.z * b.z + a.w * b.w;
}
__device__ __forceinline__ void st4T(float* ldsT, int k0, int NBp, int nl, float4 v) {
  ldsT[(k0 + 0) * NBp + nl] = v.x;
  ldsT[(k0 + 1) * NBp + nl] = v.y;
  ldsT[(k0 + 2) * NBp + nl] = v.z;
  ldsT[(k0 + 3) * NBp + nl] = v.w;
}
__device__ __forceinline__ float4 shfl4(float4 v, int e, int w) {
  return make_float4(__shfl(v.x, e, w), __shfl(v.y, e, w),
                     __shfl(v.z, e, w), __shfl(v.w, e, w));
}

// ---------------- CSR build: histogram over dst + per-edge rank ----------------
__global__ __launch_bounds__(256) void hist_kernel(const int* __restrict__ ei,
                                                   int* __restrict__ counts,
                                                   int* __restrict__ rank) {
  int e = blockIdx.x * 256 + threadIdx.x;
  if (e < NEDGES) rank[e] = atomicAdd(&counts[ei[NEDGES + e]], 1);
}

__global__ __launch_bounds__(256) void scanA_kernel(const int* __restrict__ counts,
                                                    int* __restrict__ rowptr,
                                                    int* __restrict__ blockSum) {
  __shared__ int sm[256];
  int i = blockIdx.x * 256 + threadIdx.x;
  int v = (i < NNODES) ? counts[i] : 0;
  sm[threadIdx.x] = v;
  __syncthreads();
  for (int off = 1; off < 256; off <<= 1) {
    int x = (threadIdx.x >= off) ? sm[threadIdx.x - off] : 0;
    __syncthreads();
    sm[threadIdx.x] += x;
    __syncthreads();
  }
  if (i < NNODES) rowptr[i] = sm[threadIdx.x] - v;
  if (threadIdx.x == 255) blockSum[blockIdx.x] = sm[255];
}

// merged scanB+scanC: every block redundantly scans the 196 block sums in LDS,
// then applies its exclusive offset to its rowptr slice.
__global__ __launch_bounds__(256) void scanBC_kernel(const int* __restrict__ blockSum,
                                                     int* __restrict__ rowptr) {
  __shared__ int sm[256];
  int v = (threadIdx.x < SCAN_BLOCKS) ? blockSum[threadIdx.x] : 0;
  sm[threadIdx.x] = v;
  __syncthreads();
  for (int off = 1; off < 256; off <<= 1) {
    int x = (threadIdx.x >= off) ? sm[threadIdx.x - off] : 0;
    __syncthreads();
    sm[threadIdx.x] += x;
    __syncthreads();
  }
  int off = (blockIdx.x == 0) ? 0 : sm[blockIdx.x - 1];  // exclusive prefix
  int i = blockIdx.x * 256 + threadIdx.x;
  if (i < NNODES) rowptr[i] += off;
  if (i == 0) rowptr[NNODES] = NEDGES;
}

// Atomic-free XCD-partitioned scatter.
__global__ __launch_bounds__(256) void scatter_kernel(const int* __restrict__ ei,
                                                      const int* __restrict__ rowptr,
                                                      const int* __restrict__ rank,
                                                      int* __restrict__ col) {
  const int p = blockIdx.x & 7;
  const int sl = blockIdx.x >> 3;
  const int P0 = p * NPART;
  const int e1 = min((sl + 1) * EPS, NEDGES);
  for (int e = sl * EPS + threadIdx.x; e < e1; e += 256) {
    int dst = __builtin_nontemporal_load(&ei[NEDGES + e]);
    if ((unsigned)(dst - P0) < (unsigned)NPART) {
      int pos = rowptr[dst] + __builtin_nontemporal_load(&rank[e]);
      col[pos] = __builtin_nontemporal_load(&ei[e]);
    }
  }
}

// ---------------- W pre-transpose into [k][o] rows (scalar-load friendly) ----
__global__ __launch_bounds__(256) void prep_kernel(const float* __restrict__ W1,
                                                   const float* __restrict__ W2,
                                                   const float* __restrict__ W3,
                                                   float* __restrict__ Wk1,
                                                   float* __restrict__ Wk2,
                                                   float* __restrict__ Wk3) {
  int i = blockIdx.x * 256 + threadIdx.x;
  if (i < 4096) {
    int f = i >> 6, j = i & 63;
    Wk1[i] = W1[f * 64 + ((j & 3) << 4) + (j >> 2)];
  } else if (i < 6144) {
    int i2 = i - 4096;
    int k = i2 >> 5, o = i2 & 31;
    int hh = k >> 4, f = k & 15;
    Wk2[i2] = W2[f * 128 + hh * 32 + o];
  } else if (i < 14336) {
    int i3 = i - 6144;
    int k = i3 >> 6, o = i3 & 63;
    int hh = k >> 5, f = k & 31;
    Wk3[i3] = W3[f * 256 + hh * 64 + o];
  }
}

// ---------------- layer-1 t GEMM: t[n][j] = x[n][:64] . Wk1[j][:64] ----------
template<int K, int OUTT, int MO>
__global__ __launch_bounds__(256) void ngemm_kernel(const float* __restrict__ A,
                                                    const float* __restrict__ Wk,
                                                    float* __restrict__ C) {
  constexpr int OG = OUTT / MO;
  constexpr int NB = 256 / OG;
  constexpr int NBp = NB + 1;
  __shared__ float ldsT[K * NBp];
  const int tid = threadIdx.x;
  const int nb0 = blockIdx.x * NB;
  for (int i = tid; i < NB * (K / 4); i += 256) {
    int r = i / (K / 4), kq = i - r * (K / 4);
    int n = nb0 + r;
    if (n >= NNODES) n = NNODES - 1;
    float4 v = ((const float4*)A)[n * (K / 4) + kq];
    st4T(ldsT, kq << 2, NBp, r, v);
  }
  __syncthreads();
  const int o0 = __builtin_amdgcn_readfirstlane(tid / NB) * MO;
  const int nl = tid & (NB - 1);
  const int n = nb0 + nl;
  float acc[MO];
#pragma unroll
  for (int m = 0; m < MO; ++m) acc[m] = 0.f;
#pragma unroll 4
  for (int k = 0; k < K; ++k) {
    float a = ldsT[k * NBp + nl];
    const float* wr = Wk + k * OUTT + o0;   // wave-uniform -> s_load
#pragma unroll
    for (int m = 0; m < MO; ++m) acc[m] += a * wr[m];
  }
  if (n < NNODES) {
#pragma unroll
    for (int m4 = 0; m4 < MO / 4; ++m4) {
      float4 v = make_float4(acc[m4 * 4 + 0], acc[m4 * 4 + 1],
                             acc[m4 * 4 + 2], acc[m4 * 4 + 3]);
      ((float4*)C)[n * (OUTT / 4) + (o0 >> 2) + m4] = v;
    }
  }
}

// ---------------- fused g-gather + transform (layers 2/3) ----------------
// Phase 1: gather with fused softmax (lane-split + shfl broadcast), results
// written straight into the transposed LDS tile. Phase 2: ngemm loop, /deg+
// bias+relu epilogue. (No BN-stats fusion: round 16 showed it spills -> 10x.)
template<int FIN, int OUTT, int MO>
__global__ __launch_bounds__(256) void fusedG_kernel(const int* __restrict__ rowptr,
                                                     const int* __restrict__ col,
                                                     const float* __restrict__ s,
                                                     const float* __restrict__ x,
                                                     const float* __restrict__ Wk,
                                                     const float* __restrict__ cptr,
                                                     const float* __restrict__ bptr,
                                                     float* __restrict__ h) {
  constexpr int LPN = FIN / 8;        // lanes per node (2 or 4)
  constexpr int NB = 256 / LPN;       // nodes per block (128 or 64)
  constexpr int NBp = NB + 1;
  constexpr int K = 4 * FIN;
  constexpr int OG = OUTT / MO;       // must equal 256/NB (wave-uniform o0)
  static_assert(OG == 256 / NB, "geometry mismatch");
  __shared__ float ldsT[K * NBp];
  const int tid = threadIdx.x;
  const int nb0 = blockIdx.x * NB;
  const float4* sF4 = (const float4*)s;
  const float4* xF4 = (const float4*)x;

  // ---- phase 1: gather ----
  {
    const int lane = tid & (LPN - 1);
    const int sub = tid / LPN;
    int n = nb0 + sub;
    if (n >= NNODES) n = NNODES - 1;   // duplicate work, discarded in phase 2
    float4 c4 = *(const float4*)cptr;
    float mxc = fmaxf(fmaxf(c4.x, c4.y), fmaxf(c4.z, c4.w));
    float4 qsl = make_float4(__expf(c4.x - mxc), __expf(c4.y - mxc),
                             __expf(c4.z - mxc), __expf(c4.w - mxc));
    float sinv = 1.f / (qsl.x + qsl.y + qsl.z + qsl.w);
    qsl.x *= sinv; qsl.y *= sinv; qsl.z *= sinv; qsl.w *= sinv;
    float4 sd = sF4[n];
    const float4* xn = xF4 + n * (FIN / 4) + 2 * lane;
    float4 xa = xn[0], xb = xn[1];
    float4 g0a = make_float4(qsl.x * xa.x, qsl.x * xa.y, qsl.x * xa.z, qsl.x * xa.w);
    float4 g0b = make_float4(qsl.x * xb.x, qsl.x * xb.y, qsl.x * xb.z, qsl.x * xb.w);
    float4 g1a = make_float4(qsl.y * xa.x, qsl.y * xa.y, qsl.y * xa.z, qsl.y * xa.w);
    float4 g1b = make_float4(qsl.y * xb.x, qsl.y * xb.y, qsl.y * xb.z, qsl.y * xb.w);
    float4 g2a = make_float4(qsl.z * xa.x, qsl.z * xa.y, qsl.z * xa.z, qsl.z * xa.w);
    float4 g2b = make_float4(qsl.z * xb.x, qsl.z * xb.y, qsl.z * xb.z, qsl.z * xb.w);
    float4 g3a = make_float4(qsl.w * xa.x, qsl.w * xa.y, qsl.w * xa.z, qsl.w * xa.w);
    float4 g3b = make_float4(qsl.w * xb.x, qsl.w * xb.y, qsl.w * xb.z, qsl.w * xb.w);
    const int beg = rowptr[n], end = rowptr[n + 1];
    int idx = beg;
    for (; idx + LPN <= end; idx += LPN) {
      int myS = col[idx + lane];                 // per-lane coalesced
      float4 qL = softq(sF4[myS], sd, c4);       // one softmax per lane
#pragma unroll
      for (int e = 0; e < LPN; ++e) {
        int srcE = __shfl(myS, e, LPN);
        float4 q = shfl4(qL, e, LPN);
        const float4* xr = xF4 + srcE * (FIN / 4) + 2 * lane;
        float4 x0a = xr[0], x0b = xr[1];
        fma4(g0a, q.x, x0a); fma4(g0b, q.x, x0b);
        fma4(g1a, q.y, x0a); fma4(g1b, q.y, x0b);
        fma4(g2a, q.z, x0a); fma4(g2b, q.z, x0b);
        fma4(g3a, q.w, x0a); fma4(g3b, q.w, x0b);
      }
    }
    for (; idx < end; ++idx) {
      int s0 = col[idx];
      float4 qv = softq(sF4[s0], sd, c4);
      const float4* xr = xF4 + s0 * (FIN / 4) + 2 * lane;
      float4 x0a = xr[0], x0b = xr[1];
      fma4(g0a, qv.x, x0a); fma4(g0b, qv.x, x0b);
      fma4(g1a, qv.y, x0a); fma4(g1b, qv.y, x0b);
      fma4(g2a, qv.z, x0a); fma4(g2b, qv.z, x0b);
      fma4(g3a, qv.w, x0a); fma4(g3b, qv.w, x0b);
    }
    const int f0 = 8 * lane;
    st4T(ldsT, 0 * FIN + f0, NBp, sub, g0a); st4T(ldsT, 0 * FIN + f0 + 4, NBp, sub, g0b);
    st4T(ldsT, 1 * FIN + f0, NBp, sub, g1a); st4T(ldsT, 1 * FIN + f0 + 4, NBp, sub, g1b);
    st4T(ldsT, 2 * FIN + f0, NBp, sub, g2a); st4T(ldsT, 2 * FIN + f0 + 4, NBp, sub, g2b);
    st4T(ldsT, 3 * FIN + f0, NBp, sub, g3a); st4T(ldsT, 3 * FIN + f0 + 4, NBp, sub, g3b);
  }
  __syncthreads();

  // ---- phase 2: transform ----
  const int o0 = __builtin_amdgcn_readfirstlane(tid / NB) * MO;
  const int nl = tid & (NB - 1);
  const int n = nb0 + nl;
  float acc[MO];
#pragma unroll
  for (int m = 0; m < MO; ++m) acc[m] = 0.f;
#pragma unroll 4
  for (int k = 0; k < K; ++k) {
    float a = ldsT[k * NBp + nl];
    const float* wr = Wk + k * OUTT + o0;   // wave-uniform -> s_load
#pragma unroll
    for (int m = 0; m < MO; ++m) acc[m] += a * wr[m];
  }
  if (n < NNODES) {
    float sc = 1.f / (float)(rowptr[n + 1] - rowptr[n] + 1);
#pragma unroll
    for (int m4 = 0; m4 < MO / 4; ++m4) {
      float4 v;
      v.x = fmaxf(acc[m4 * 4 + 0] * sc + bptr[o0 + m4 * 4 + 0], 0.f);
      v.y = fmaxf(acc[m4 * 4 + 1] * sc + bptr[o0 + m4 * 4 + 1], 0.f);
      v.z = fmaxf(acc[m4 * 4 + 2] * sc + bptr[o0 + m4 * 4 + 2], 0.f);
      v.w = fmaxf(acc[m4 * 4 + 3] * sc + bptr[o0 + m4 * 4 + 3], 0.f);
      ((float4*)h)[n * (OUTT / 4) + (o0 >> 2) + m4] = v;
    }
  }
}

// ---------------- s = x @ u  ([N,4]) ----------------
template<int FIN>
__global__ __launch_bounds__(256) void s_kernel(const float* __restrict__ x,
                                                const float* __restrict__ u,
                                                float* __restrict__ s) {
  int tid = blockIdx.x * 256 + threadIdx.x;
  int n = tid >> 2, h = tid & 3;
  if (n >= NNODES) return;
  const float4* xr = (const float4*)x + n * (FIN / 4);
  float acc = 0.f;
#pragma unroll
  for (int f4 = 0; f4 < FIN / 4; ++f4) {
    float4 xv = xr[f4];
    acc += xv.x * u[(4 * f4 + 0) * 4 + h] + xv.y * u[(4 * f4 + 1) * 4 + h] +
           xv.z * u[(4 * f4 + 2) * 4 + h] + xv.w * u[(4 * f4 + 3) * 4 + h];
  }
  s[tid] = acc;  // tid == n*4+h
}

// ---------------- layer-1 gather over t, fused softmax + shfl dedup ----------
__global__ __launch_bounds__(256) void gather1_kernel(const int* __restrict__ rowptr,
                                                      const int* __restrict__ col,
                                                      const float* __restrict__ s,
                                                      const float* __restrict__ t,
                                                      const float* __restrict__ cptr,
                                                      const float* __restrict__ bptr,
                                                      float* __restrict__ h) {
  const int lane = threadIdx.x & 7;
  const int sub = threadIdx.x >> 3;
  const int n = blockIdx.x * 32 + sub;
  if (n >= NNODES) return;
  const float4* sF4 = (const float4*)s;
  const float4* tF4 = (const float4*)t;
  float4 c4 = *(const float4*)cptr;
  float mxc = fmaxf(fmaxf(c4.x, c4.y), fmaxf(c4.z, c4.w));
  float4 qs = make_float4(__expf(c4.x - mxc), __expf(c4.y - mxc),
                          __expf(c4.z - mxc), __expf(c4.w - mxc));
  float sinv = 1.f / (qs.x + qs.y + qs.z + qs.w);
  qs.x *= sinv; qs.y *= sinv; qs.z *= sinv; qs.w *= sinv;
  float4 sd = sF4[n];
  const float4* trow = tF4 + n * 16 + 2 * lane;
  float acc0 = dot4(qs, trow[0]);
  float acc1 = dot4(qs, trow[1]);
  const int beg = rowptr[n], end = rowptr[n + 1];
  int idx = beg;
  for (; idx + 8 <= end; idx += 8) {
    int myS = col[idx + lane];                 // per-lane coalesced
    float4 qL = softq(sF4[myS], sd, c4);       // one softmax per lane
#pragma unroll
    for (int e = 0; e < 8; ++e) {
      int srcE = __shfl(myS, e, 8);
      float4 q = shfl4(qL, e, 8);
      const float4* tw = tF4 + srcE * 16 + 2 * lane;
      acc0 += dot4(q, tw[0]);
      acc1 += dot4(q, tw[1]);
    }
  }
  for (; idx < end; ++idx) {
    int src = col[idx];
    float4 qv = softq(sF4[src], sd, c4);
    const float4* tw = tF4 + src * 16 + 2 * lane;
    acc0 += dot4(qv, tw[0]);
    acc1 += dot4(qv, tw[1]);
  }
  float d = 1.f / (float)(end - beg + 1);
  h[n * 16 + 2 * lane + 0] = fmaxf(acc0 * d + bptr[2 * lane + 0], 0.f);
  h[n * 16 + 2 * lane + 1] = fmaxf(acc1 * d + bptr[2 * lane + 1], 0.f);
}

// ---------------- BN batch-stats over h3 [N,64] ----------------
__global__ __launch_bounds__(256) void stats_kernel(const float* __restrict__ h3,
                                                    float* __restrict__ sums) {
  const int o = threadIdx.x & 63;
  const int r = threadIdx.x >> 6;
  float accS = 0.f, accQ = 0.f;
  for (int base = blockIdx.x * 4; base < NNODES; base += gridDim.x * 4) {
    int n = base + r;
    if (n < NNODES) {
      float v = h3[n * 64 + o];
      accS += v;
      accQ += v * v;
    }
  }
  __shared__ float ls[256], lq[256];
  ls[threadIdx.x] = accS;
  lq[threadIdx.x] = accQ;
  __syncthreads();
  if (threadIdx.x < 64) {
    float a = ls[threadIdx.x] + ls[threadIdx.x + 64] + ls[threadIdx.x + 128] + ls[threadIdx.x + 192];
    float qq = lq[threadIdx.x] + lq[threadIdx.x + 64] + lq[threadIdx.x + 128] + lq[threadIdx.x + 192];
    atomicAdd(&sums[threadIdx.x], a);
    atomicAdd(&sums[64 + threadIdx.x], qq);
  }
}

// ---------------- BN + MLP head + sigmoid, one thread per node ----------------
__global__ __launch_bounds__(256) void mlp_kernel(
    const float* __restrict__ h3, const float* __restrict__ sums,
    const float* __restrict__ gamma, const float* __restrict__ beta,
    const float* __restrict__ lw1, const float* __restrict__ lb1,
    const float* __restrict__ lw2, const float* __restrict__ lb2,
    const float* __restrict__ lw3, const float* __restrict__ lb3,
    const float* __restrict__ lw4, const float* __restrict__ lb4,
    const float* __restrict__ ow, const float* __restrict__ ob,
    float* __restrict__ out) {
  __shared__ float w1[64 * 32], w2[32 * 16], w3[16 * 8], w4[8 * 4];
  __shared__ float b1s[32], b2s[16], b3s[8], b4s[4], wos[4];
  __shared__ float scale[64], shift[64];
  int tid = threadIdx.x;
  for (int i = tid; i < 64 * 32; i += 256) w1[i] = lw1[i];
  for (int i = tid; i < 32 * 16; i += 256) w2[i] = lw2[i];
  if (tid < 128) w3[tid] = lw3[tid];
  if (tid < 32) { w4[tid] = lw4[tid]; b1s[tid] = lb1[tid]; }
  if (tid < 16) b2s[tid] = lb2[tid];
  if (tid < 8) b3s[tid] = lb3[tid];
  if (tid < 4) { b4s[tid] = lb4[tid]; wos[tid] = ow[tid]; }
  if (tid < 64) {
    float mu = sums[tid] * (1.f / NNODES);
    float var = sums[64 + tid] * (1.f / NNODES) - mu * mu;
    float sc = rsqrtf(var + 1e-5f) * gamma[tid];
    scale[tid] = sc;
    shift[tid] = beta[tid] - mu * sc;
  }
  __syncthreads();
  int n = blockIdx.x * 256 + tid;
  if (n >= NNODES) return;
  float obv = ob[0];
  const float4* hr = (const float4*)h3 + n * 16;
  float z1[32];
#pragma unroll
  for (int j = 0; j < 32; ++j) z1[j] = b1s[j];
  for (int i4 = 0; i4 < 16; ++i4) {
    float4 hv = hr[i4];
    float a0 = hv.x * scale[4 * i4 + 0] + shift[4 * i4 + 0];
    float a1 = hv.y * scale[4 * i4 + 1] + shift[4 * i4 + 1];
    float a2 = hv.z * scale[4 * i4 + 2] + shift[4 * i4 + 2];
    float a3 = hv.w * scale[4 * i4 + 3] + shift[4 * i4 + 3];
#pragma unroll
    for (int j = 0; j < 32; ++j) {
      z1[j] += a0 * w1[(4 * i4 + 0) * 32 + j] + a1 * w1[(4 * i4 + 1) * 32 + j] +
               a2 * w1[(4 * i4 + 2) * 32 + j] + a3 * w1[(4 * i4 + 3) * 32 + j];
    }
  }
  float z2[16];
#pragma unroll
  for (int j = 0; j < 16; ++j) z2[j] = b2s[j];
  for (int i = 0; i < 32; ++i) {
    float a = fmaxf(z1[i], 0.f);
#pragma unroll
    for (int j = 0; j < 16; ++j) z2[j] += a * w2[i * 16 + j];
  }
  float z3[8];
#pragma unroll
  for (int j = 0; j < 8; ++j) z3[j] = b3s[j];
  for (int i = 0; i < 16; ++i) {
    float a = fmaxf(z2[i], 0.f);
#pragma unroll
    for (int j = 0; j < 8; ++j) z3[j] += a * w3[i * 8 + j];
  }
  float z4[4];
#pragma unroll
  for (int j = 0; j < 4; ++j) z4[j] = b4s[j];
  for (int i = 0; i < 8; ++i) {
    float a = fmaxf(z3[i], 0.f);
#pragma unroll
    for (int j = 0; j < 4; ++j) z4[j] += a * w4[i * 4 + j];
  }
  float zo = obv;
#pragma unroll
  for (int i = 0; i < 4; ++i) zo += fmaxf(z4[i], 0.f) * wos[i];
  out[n] = 1.f / (1.f + __expf(-zo));
}

extern "C" void kernel_launch(void* const* d_in, const int* in_sizes, int n_in,
                              void* d_out, int out_size, void* d_ws, size_t ws_size,
                              hipStream_t stream) {
  const float* x  = (const float*)d_in[0];
  const int*   ei = (const int*)d_in[1];
  const float* W1 = (const float*)d_in[2];  const float* u1 = (const float*)d_in[3];
  const float* c1 = (const float*)d_in[4];  const float* b1 = (const float*)d_in[5];
  const float* W2 = (const float*)d_in[6];  const float* u2 = (const float*)d_in[7];
  const float* c2 = (const float*)d_in[8];  const float* b2 = (const float*)d_in[9];
  const float* W3 = (const float*)d_in[10]; const float* u3 = (const float*)d_in[11];
  const float* c3 = (const float*)d_in[12]; const float* b3 = (const float*)d_in[13];
  const float* gamma = (const float*)d_in[14]; const float* beta = (const float*)d_in[15];
  const float* lw1 = (const float*)d_in[16]; const float* lb1 = (const float*)d_in[17];
  const float* lw2 = (const float*)d_in[18]; const float* lb2 = (const float*)d_in[19];
  const float* lw3 = (const float*)d_in[20]; const float* lb3 = (const float*)d_in[21];
  const float* lw4 = (const float*)d_in[22]; const float* lb4 = (const float*)d_in[23];
  const float* ow  = (const float*)d_in[24]; const float* ob  = (const float*)d_in[25];
  float* out = (float*)d_out;

  float* t    = (float*)d_ws;                         // N*64   (layer-1 t)
  float* hA   = t + (size_t)NNODES * 64;              // N*64
  float* hB   = hA + (size_t)NNODES * 64;             // N*64
  float* s    = hB + (size_t)NNODES * 64;             // N*4
  float* sums = s + (size_t)NNODES * 4;               // 128
  float* Wk1  = sums + 128;                           // 4096
  float* Wk2  = Wk1 + 4096;                           // 2048
  float* Wk3  = Wk2 + 2048;                           // 8192
  int*   rowptr   = (int*)(Wk3 + 8192);               // N+1 (pad 8)
  int*   counts   = rowptr + NNODES + 8;              // N
  int*   blockSum = counts + NNODES;                  // 256
  int*   col      = blockSum + 256;                   // E
  int*   rank     = col + NEDGES;                     // E

  hipMemsetAsync(counts, 0, NNODES * sizeof(int), stream);
  hipMemsetAsync(sums, 0, 128 * sizeof(float), stream);

  // ---- W transposes + CSR by dst ----
  prep_kernel<<<56, 256, 0, stream>>>(W1, W2, W3, Wk1, Wk2, Wk3);
  hist_kernel<<<(NEDGES + 255) / 256, 256, 0, stream>>>(ei, counts, rank);
  scanA_kernel<<<SCAN_BLOCKS, 256, 0, stream>>>(counts, rowptr, blockSum);
  scanBC_kernel<<<SCAN_BLOCKS, 256, 0, stream>>>(blockSum, rowptr);
  scatter_kernel<<<NSLICE * 8, 256, 0, stream>>>(ei, rowptr, rank, col);

  // ---- layer 1: 64 -> 16 (t-gather, fused softmax) ----
  ngemm_kernel<64, 64, 16><<<(NNODES + 63) / 64, 256, 0, stream>>>(x, Wk1, t);
  s_kernel<64><<<(NNODES * 4 + 255) / 256, 256, 0, stream>>>(x, u1, s);
  gather1_kernel<<<(NNODES + 31) / 32, 256, 0, stream>>>(rowptr, col, s, t, c1, b1, hA);

  // ---- layer 2: 16 -> 32 (fused gather+transform) ----
  s_kernel<16><<<(NNODES * 4 + 255) / 256, 256, 0, stream>>>(hA, u2, s);
  fusedG_kernel<16, 32, 16><<<(NNODES + 127) / 128, 256, 0, stream>>>(
      rowptr, col, s, hA, Wk2, c2, b2, hB);

  // ---- layer 3: 32 -> 64 (fused gather+transform) ----
  s_kernel<32><<<(NNODES * 4 + 255) / 256, 256, 0, stream>>>(hB, u3, s);
  fusedG_kernel<32, 64, 16><<<(NNODES + 63) / 64, 256, 0, stream>>>(
      rowptr, col, s, hB, Wk3, c3, b3, hA);

  // ---- BN stats + MLP head ----
  stats_kernel<<<256, 256, 0, stream>>>(hA, sums);
  mlp_kernel<<<(NNODES + 255) / 256, 256, 0, stream>>>(hA, sums, gamma, beta, lw1, lb1,
                                                       lw2, lb2, lw3, lb3, lw4, lb4,
                                                       ow, ob, out);
}

// Round 18
// 237.161 us; speedup vs baseline: 2.1793x; 1.0182x over previous
//
#include <hip/hip_runtime.h>

#define NNODES 50000
#define NEDGES 800000
#define SCAN_BLOCKS ((NNODES + 255) / 256)   // 196
#define NPART (NNODES / 8)                   // 6250 nodes per XCD partition
#define EPS 2048                             // edges per slice
#define NSLICE ((NEDGES + EPS - 1) / EPS)    // 391

typedef unsigned short u16;

// per-edge attention weights: softmax over heads of (s_src - s_dst + c)
__device__ __forceinline__ float4 softq(float4 ss, float4 sd, float4 c4) {
  float l0 = ss.x - sd.x + c4.x;
  float l1 = ss.y - sd.y + c4.y;
  float l2 = ss.z - sd.z + c4.z;
  float l3 = ss.w - sd.w + c4.w;
  float mx = fmaxf(fmaxf(l0, l1), fmaxf(l2, l3));
  float e0 = __expf(l0 - mx), e1 = __expf(l1 - mx);
  float e2 = __expf(l2 - mx), e3 = __expf(l3 - mx);
  float inv = 1.f / (e0 + e1 + e2 + e3);
  return make_float4(e0 * inv, e1 * inv, e2 * inv, e3 * inv);
}

__device__ __forceinline__ void fma4(float4& a, float q, float4 v) {
  a.x += q * v.x; a.y += q * v.y; a.z += q * v.z; a.w += q * v.w;
}
__device__ __forceinline__ float dot4(float4 a, float4 b) {
  return a.x * b.x + a.y * b.y + a.z * b.z + a.w * b.w;
}
__device__ __forceinline__ void st4T(float* ldsT, int k0, int NBp, int nl, float4 v) {
  ldsT[(k0 + 0) * NBp + nl] = v.x;
  ldsT[(k0 + 1) * NBp + nl] = v.y;
  ldsT[(k0 + 2) * NBp + nl] = v.z;
  ldsT[(k0 + 3) * NBp + nl] = v.w;
}
__device__ __forceinline__ float4 shfl4(float4 v, int e, int w) {
  return make_float4(__shfl(v.x, e, w), __shfl(v.y, e, w),
                     __shfl(v.z, e, w), __shfl(v.w, e, w));
}

// ---------------- CSR build: histogram over dst + per-edge rank (u16) --------
__global__ __launch_bounds__(256) void hist_kernel(const int* __restrict__ ei,
                                                   int* __restrict__ counts,
                                                   u16* __restrict__ rank) {
  int e = blockIdx.x * 256 + threadIdx.x;
  if (e < NEDGES) rank[e] = (u16)atomicAdd(&counts[ei[NEDGES + e]], 1);
}

__global__ __launch_bounds__(256) void scanA_kernel(const int* __restrict__ counts,
                                                    int* __restrict__ rowptr,
                                                    int* __restrict__ blockSum) {
  __shared__ int sm[256];
  int i = blockIdx.x * 256 + threadIdx.x;
  int v = (i < NNODES) ? counts[i] : 0;
  sm[threadIdx.x] = v;
  __syncthreads();
  for (int off = 1; off < 256; off <<= 1) {
    int x = (threadIdx.x >= off) ? sm[threadIdx.x - off] : 0;
    __syncthreads();
    sm[threadIdx.x] += x;
    __syncthreads();
  }
  if (i < NNODES) rowptr[i] = sm[threadIdx.x] - v;
  if (threadIdx.x == 255) blockSum[blockIdx.x] = sm[255];
}

// merged scanB+scanC: every block redundantly scans the 196 block sums in LDS,
// then applies its exclusive offset to its rowptr slice.
__global__ __launch_bounds__(256) void scanBC_kernel(const int* __restrict__ blockSum,
                                                     int* __restrict__ rowptr) {
  __shared__ int sm[256];
  int v = (threadIdx.x < SCAN_BLOCKS) ? blockSum[threadIdx.x] : 0;
  sm[threadIdx.x] = v;
  __syncthreads();
  for (int off = 1; off < 256; off <<= 1) {
    int x = (threadIdx.x >= off) ? sm[threadIdx.x - off] : 0;
    __syncthreads();
    sm[threadIdx.x] += x;
    __syncthreads();
  }
  int off = (blockIdx.x == 0) ? 0 : sm[blockIdx.x - 1];  // exclusive prefix
  int i = blockIdx.x * 256 + threadIdx.x;
  if (i < NNODES) rowptr[i] += off;
  if (i == 0) rowptr[NNODES] = NEDGES;
}

// Atomic-free XCD-partitioned scatter; u16 col halves writeback amplification.
__global__ __launch_bounds__(256) void scatter_kernel(const int* __restrict__ ei,
                                                      const int* __restrict__ rowptr,
                                                      const u16* __restrict__ rank,
                                                      u16* __restrict__ col) {
  const int p = blockIdx.x & 7;
  const int sl = blockIdx.x >> 3;
  const int P0 = p * NPART;
  const int e1 = min((sl + 1) * EPS, NEDGES);
  for (int e = sl * EPS + threadIdx.x; e < e1; e += 256) {
    int dst = __builtin_nontemporal_load(&ei[NEDGES + e]);
    if ((unsigned)(dst - P0) < (unsigned)NPART) {
      int pos = rowptr[dst] + (int)__builtin_nontemporal_load(&rank[e]);
      col[pos] = (u16)__builtin_nontemporal_load(&ei[e]);
    }
  }
}

// ---------------- W pre-transpose into [k][o] rows (scalar-load friendly) ----
__global__ __launch_bounds__(256) void prep_kernel(const float* __restrict__ W1,
                                                   const float* __restrict__ W2,
                                                   const float* __restrict__ W3,
                                                   float* __restrict__ Wk1,
                                                   float* __restrict__ Wk2,
                                                   float* __restrict__ Wk3) {
  int i = blockIdx.x * 256 + threadIdx.x;
  if (i < 4096) {
    int f = i >> 6, j = i & 63;
    Wk1[i] = W1[f * 64 + ((j & 3) << 4) + (j >> 2)];
  } else if (i < 6144) {
    int i2 = i - 4096;
    int k = i2 >> 5, o = i2 & 31;
    int hh = k >> 4, f = k & 15;
    Wk2[i2] = W2[f * 128 + hh * 32 + o];
  } else if (i < 14336) {
    int i3 = i - 6144;
    int k = i3 >> 6, o = i3 & 63;
    int hh = k >> 5, f = k & 31;
    Wk3[i3] = W3[f * 256 + hh * 64 + o];
  }
}

// ---------------- layer-1 t GEMM: t[n][j] = x[n][:64] . Wk1[j][:64] ----------
template<int K, int OUTT, int MO>
__global__ __launch_bounds__(256) void ngemm_kernel(const float* __restrict__ A,
                                                    const float* __restrict__ Wk,
                                                    float* __restrict__ C) {
  constexpr int OG = OUTT / MO;
  constexpr int NB = 256 / OG;
  constexpr int NBp = NB + 1;
  __shared__ float ldsT[K * NBp];
  const int tid = threadIdx.x;
  const int nb0 = blockIdx.x * NB;
  for (int i = tid; i < NB * (K / 4); i += 256) {
    int r = i / (K / 4), kq = i - r * (K / 4);
    int n = nb0 + r;
    if (n >= NNODES) n = NNODES - 1;
    float4 v = ((const float4*)A)[n * (K / 4) + kq];
    st4T(ldsT, kq << 2, NBp, r, v);
  }
  __syncthreads();
  const int o0 = __builtin_amdgcn_readfirstlane(tid / NB) * MO;
  const int nl = tid & (NB - 1);
  const int n = nb0 + nl;
  float acc[MO];
#pragma unroll
  for (int m = 0; m < MO; ++m) acc[m] = 0.f;
#pragma unroll 4
  for (int k = 0; k < K; ++k) {
    float a = ldsT[k * NBp + nl];
    const float* wr = Wk + k * OUTT + o0;   // wave-uniform -> s_load
#pragma unroll
    for (int m = 0; m < MO; ++m) acc[m] += a * wr[m];
  }
  if (n < NNODES) {
#pragma unroll
    for (int m4 = 0; m4 < MO / 4; ++m4) {
      float4 v = make_float4(acc[m4 * 4 + 0], acc[m4 * 4 + 1],
                             acc[m4 * 4 + 2], acc[m4 * 4 + 3]);
      ((float4*)C)[n * (OUTT / 4) + (o0 >> 2) + m4] = v;
    }
  }
}

// ---------------- fused g-gather + transform (layers 2/3) ----------------
// Phase 1: gather with fused softmax (lane-split + shfl broadcast), results
// written straight into the transposed LDS tile. Phase 2: ngemm loop, /deg+
// bias+relu epilogue. (No BN-stats fusion: round 16 showed it spills -> 10x.)
template<int FIN, int OUTT, int MO>
__global__ __launch_bounds__(256) void fusedG_kernel(const int* __restrict__ rowptr,
                                                     const u16* __restrict__ col,
                                                     const float* __restrict__ s,
                                                     const float* __restrict__ x,
                                                     const float* __restrict__ Wk,
                                                     const float* __restrict__ cptr,
                                                     const float* __restrict__ bptr,
                                                     float* __restrict__ h) {
  constexpr int LPN = FIN / 8;        // lanes per node (2 or 4)
  constexpr int NB = 256 / LPN;       // nodes per block (128 or 64)
  constexpr int NBp = NB + 1;
  constexpr int K = 4 * FIN;
  constexpr int OG = OUTT / MO;       // must equal 256/NB (wave-uniform o0)
  static_assert(OG == 256 / NB, "geometry mismatch");
  __shared__ float ldsT[K * NBp];
  const int tid = threadIdx.x;
  const int nb0 = blockIdx.x * NB;
  const float4* sF4 = (const float4*)s;
  const float4* xF4 = (const float4*)x;

  // ---- phase 1: gather ----
  {
    const int lane = tid & (LPN - 1);
    const int sub = tid / LPN;
    int n = nb0 + sub;
    if (n >= NNODES) n = NNODES - 1;   // duplicate work, discarded in phase 2
    float4 c4 = *(const float4*)cptr;
    float mxc = fmaxf(fmaxf(c4.x, c4.y), fmaxf(c4.z, c4.w));
    float4 qsl = make_float4(__expf(c4.x - mxc), __expf(c4.y - mxc),
                             __expf(c4.z - mxc), __expf(c4.w - mxc));
    float sinv = 1.f / (qsl.x + qsl.y + qsl.z + qsl.w);
    qsl.x *= sinv; qsl.y *= sinv; qsl.z *= sinv; qsl.w *= sinv;
    float4 sd = sF4[n];
    const float4* xn = xF4 + n * (FIN / 4) + 2 * lane;
    float4 xa = xn[0], xb = xn[1];
    float4 g0a = make_float4(qsl.x * xa.x, qsl.x * xa.y, qsl.x * xa.z, qsl.x * xa.w);
    float4 g0b = make_float4(qsl.x * xb.x, qsl.x * xb.y, qsl.x * xb.z, qsl.x * xb.w);
    float4 g1a = make_float4(qsl.y * xa.x, qsl.y * xa.y, qsl.y * xa.z, qsl.y * xa.w);
    float4 g1b = make_float4(qsl.y * xb.x, qsl.y * xb.y, qsl.y * xb.z, qsl.y * xb.w);
    float4 g2a = make_float4(qsl.z * xa.x, qsl.z * xa.y, qsl.z * xa.z, qsl.z * xa.w);
    float4 g2b = make_float4(qsl.z * xb.x, qsl.z * xb.y, qsl.z * xb.z, qsl.z * xb.w);
    float4 g3a = make_float4(qsl.w * xa.x, qsl.w * xa.y, qsl.w * xa.z, qsl.w * xa.w);
    float4 g3b = make_float4(qsl.w * xb.x, qsl.w * xb.y, qsl.w * xb.z, qsl.w * xb.w);
    const int beg = rowptr[n], end = rowptr[n + 1];
    int idx = beg;
    for (; idx + LPN <= end; idx += LPN) {
      int myS = (int)col[idx + lane];             // per-lane coalesced
      float4 qL = softq(sF4[myS], sd, c4);        // one softmax per lane
#pragma unroll
      for (int e = 0; e < LPN; ++e) {
        int srcE = __shfl(myS, e, LPN);
        float4 q = shfl4(qL, e, LPN);
        const float4* xr = xF4 + srcE * (FIN / 4) + 2 * lane;
        float4 x0a = xr[0], x0b = xr[1];
        fma4(g0a, q.x, x0a); fma4(g0b, q.x, x0b);
        fma4(g1a, q.y, x0a); fma4(g1b, q.y, x0b);
        fma4(g2a, q.z, x0a); fma4(g2b, q.z, x0b);
        fma4(g3a, q.w, x0a); fma4(g3b, q.w, x0b);
      }
    }
    for (; idx < end; ++idx) {
      int s0 = (int)col[idx];
      float4 qv = softq(sF4[s0], sd, c4);
      const float4* xr = xF4 + s0 * (FIN / 4) + 2 * lane;
      float4 x0a = xr[0], x0b = xr[1];
      fma4(g0a, qv.x, x0a); fma4(g0b, qv.x, x0b);
      fma4(g1a, qv.y, x0a); fma4(g1b, qv.y, x0b);
      fma4(g2a, qv.z, x0a); fma4(g2b, qv.z, x0b);
      fma4(g3a, qv.w, x0a); fma4(g3b, qv.w, x0b);
    }
    const int f0 = 8 * lane;
    st4T(ldsT, 0 * FIN + f0, NBp, sub, g0a); st4T(ldsT, 0 * FIN + f0 + 4, NBp, sub, g0b);
    st4T(ldsT, 1 * FIN + f0, NBp, sub, g1a); st4T(ldsT, 1 * FIN + f0 + 4, NBp, sub, g1b);
    st4T(ldsT, 2 * FIN + f0, NBp, sub, g2a); st4T(ldsT, 2 * FIN + f0 + 4, NBp, sub, g2b);
    st4T(ldsT, 3 * FIN + f0, NBp, sub, g3a); st4T(ldsT, 3 * FIN + f0 + 4, NBp, sub, g3b);
  }
  __syncthreads();

  // ---- phase 2: transform ----
  const int o0 = __builtin_amdgcn_readfirstlane(tid / NB) * MO;
  const int nl = tid & (NB - 1);
  const int n = nb0 + nl;
  float acc[MO];
#pragma unroll
  for (int m = 0; m < MO; ++m) acc[m] = 0.f;
#pragma unroll 4
  for (int k = 0; k < K; ++k) {
    float a = ldsT[k * NBp + nl];
    const float* wr = Wk + k * OUTT + o0;   // wave-uniform -> s_load
#pragma unroll
    for (int m = 0; m < MO; ++m) acc[m] += a * wr[m];
  }
  if (n < NNODES) {
    float sc = 1.f / (float)(rowptr[n + 1] - rowptr[n] + 1);
#pragma unroll
    for (int m4 = 0; m4 < MO / 4; ++m4) {
      float4 v;
      v.x = fmaxf(acc[m4 * 4 + 0] * sc + bptr[o0 + m4 * 4 + 0], 0.f);
      v.y = fmaxf(acc[m4 * 4 + 1] * sc + bptr[o0 + m4 * 4 + 1], 0.f);
      v.z = fmaxf(acc[m4 * 4 + 2] * sc + bptr[o0 + m4 * 4 + 2], 0.f);
      v.w = fmaxf(acc[m4 * 4 + 3] * sc + bptr[o0 + m4 * 4 + 3], 0.f);
      ((float4*)h)[n * (OUTT / 4) + (o0 >> 2) + m4] = v;
    }
  }
}

// ---------------- s = x @ u  ([N,4]) ----------------
template<int FIN>
__global__ __launch_bounds__(256) void s_kernel(const float* __restrict__ x,
                                                const float* __restrict__ u,
                                                float* __restrict__ s) {
  int tid = blockIdx.x * 256 + threadIdx.x;
  int n = tid >> 2, h = tid & 3;
  if (n >= NNODES) return;
  const float4* xr = (const float4*)x + n * (FIN / 4);
  float acc = 0.f;
#pragma unroll
  for (int f4 = 0; f4 < FIN / 4; ++f4) {
    float4 xv = xr[f4];
    acc += xv.x * u[(4 * f4 + 0) * 4 + h] + xv.y * u[(4 * f4 + 1) * 4 + h] +
           xv.z * u[(4 * f4 + 2) * 4 + h] + xv.w * u[(4 * f4 + 3) * 4 + h];
  }
  s[tid] = acc;  // tid == n*4+h
}

// ---------------- layer-1 gather over t, fused softmax + shfl dedup ----------
__global__ __launch_bounds__(256) void gather1_kernel(const int* __restrict__ rowptr,
                                                      const u16* __restrict__ col,
                                                      const float* __restrict__ s,
                                                      const float* __restrict__ t,
                                                      const float* __restrict__ cptr,
                                                      const float* __restrict__ bptr,
                                                      float* __restrict__ h) {
  const int lane = threadIdx.x & 7;
  const int sub = threadIdx.x >> 3;
  const int n = blockIdx.x * 32 + sub;
  if (n >= NNODES) return;
  const float4* sF4 = (const float4*)s;
  const float4* tF4 = (const float4*)t;
  float4 c4 = *(const float4*)cptr;
  float mxc = fmaxf(fmaxf(c4.x, c4.y), fmaxf(c4.z, c4.w));
  float4 qs = make_float4(__expf(c4.x - mxc), __expf(c4.y - mxc),
                          __expf(c4.z - mxc), __expf(c4.w - mxc));
  float sinv = 1.f / (qs.x + qs.y + qs.z + qs.w);
  qs.x *= sinv; qs.y *= sinv; qs.z *= sinv; qs.w *= sinv;
  float4 sd = sF4[n];
  const float4* trow = tF4 + n * 16 + 2 * lane;
  float acc0 = dot4(qs, trow[0]);
  float acc1 = dot4(qs, trow[1]);
  const int beg = rowptr[n], end = rowptr[n + 1];
  int idx = beg;
  for (; idx + 8 <= end; idx += 8) {
    int myS = (int)col[idx + lane];            // per-lane coalesced
    float4 qL = softq(sF4[myS], sd, c4);       // one softmax per lane
#pragma unroll
    for (int e = 0; e < 8; ++e) {
      int srcE = __shfl(myS, e, 8);
      float4 q = shfl4(qL, e, 8);
      const float4* tw = tF4 + srcE * 16 + 2 * lane;
      acc0 += dot4(q, tw[0]);
      acc1 += dot4(q, tw[1]);
    }
  }
  for (; idx < end; ++idx) {
    int src = (int)col[idx];
    float4 qv = softq(sF4[src], sd, c4);
    const float4* tw = tF4 + src * 16 + 2 * lane;
    acc0 += dot4(qv, tw[0]);
    acc1 += dot4(qv, tw[1]);
  }
  float d = 1.f / (float)(end - beg + 1);
  h[n * 16 + 2 * lane + 0] = fmaxf(acc0 * d + bptr[2 * lane + 0], 0.f);
  h[n * 16 + 2 * lane + 1] = fmaxf(acc1 * d + bptr[2 * lane + 1], 0.f);
}

// ---------------- BN batch-stats over h3 [N,64] ----------------
__global__ __launch_bounds__(256) void stats_kernel(const float* __restrict__ h3,
                                                    float* __restrict__ sums) {
  const int o = threadIdx.x & 63;
  const int r = threadIdx.x >> 6;
  float accS = 0.f, accQ = 0.f;
  for (int base = blockIdx.x * 4; base < NNODES; base += gridDim.x * 4) {
    int n = base + r;
    if (n < NNODES) {
      float v = h3[n * 64 + o];
      accS += v;
      accQ += v * v;
    }
  }
  __shared__ float ls[256], lq[256];
  ls[threadIdx.x] = accS;
  lq[threadIdx.x] = accQ;
  __syncthreads();
  if (threadIdx.x < 64) {
    float a = ls[threadIdx.x] + ls[threadIdx.x + 64] + ls[threadIdx.x + 128] + ls[threadIdx.x + 192];
    float qq = lq[threadIdx.x] + lq[threadIdx.x + 64] + lq[threadIdx.x + 128] + lq[threadIdx.x + 192];
    atomicAdd(&sums[threadIdx.x], a);
    atomicAdd(&sums[64 + threadIdx.x], qq);
  }
}

// ---------------- BN + MLP head + sigmoid, one thread per node ----------------
__global__ __launch_bounds__(256) void mlp_kernel(
    const float* __restrict__ h3, const float* __restrict__ sums,
    const float* __restrict__ gamma, const float* __restrict__ beta,
    const float* __restrict__ lw1, const float* __restrict__ lb1,
    const float* __restrict__ lw2, const float* __restrict__ lb2,
    const float* __restrict__ lw3, const float* __restrict__ lb3,
    const float* __restrict__ lw4, const float* __restrict__ lb4,
    const float* __restrict__ ow, const float* __restrict__ ob,
    float* __restrict__ out) {
  __shared__ float w1[64 * 32], w2[32 * 16], w3[16 * 8], w4[8 * 4];
  __shared__ float b1s[32], b2s[16], b3s[8], b4s[4], wos[4];
  __shared__ float scale[64], shift[64];
  int tid = threadIdx.x;
  for (int i = tid; i < 64 * 32; i += 256) w1[i] = lw1[i];
  for (int i = tid; i < 32 * 16; i += 256) w2[i] = lw2[i];
  if (tid < 128) w3[tid] = lw3[tid];
  if (tid < 32) { w4[tid] = lw4[tid]; b1s[tid] = lb1[tid]; }
  if (tid < 16) b2s[tid] = lb2[tid];
  if (tid < 8) b3s[tid] = lb3[tid];
  if (tid < 4) { b4s[tid] = lb4[tid]; wos[tid] = ow[tid]; }
  if (tid < 64) {
    float mu = sums[tid] * (1.f / NNODES);
    float var = sums[64 + tid] * (1.f / NNODES) - mu * mu;
    float sc = rsqrtf(var + 1e-5f) * gamma[tid];
    scale[tid] = sc;
    shift[tid] = beta[tid] - mu * sc;
  }
  __syncthreads();
  int n = blockIdx.x * 256 + tid;
  if (n >= NNODES) return;
  float obv = ob[0];
  const float4* hr = (const float4*)h3 + n * 16;
  float z1[32];
#pragma unroll
  for (int j = 0; j < 32; ++j) z1[j] = b1s[j];
  for (int i4 = 0; i4 < 16; ++i4) {
    float4 hv = hr[i4];
    float a0 = hv.x * scale[4 * i4 + 0] + shift[4 * i4 + 0];
    float a1 = hv.y * scale[4 * i4 + 1] + shift[4 * i4 + 1];
    float a2 = hv.z * scale[4 * i4 + 2] + shift[4 * i4 + 2];
    float a3 = hv.w * scale[4 * i4 + 3] + shift[4 * i4 + 3];
#pragma unroll
    for (int j = 0; j < 32; ++j) {
      z1[j] += a0 * w1[(4 * i4 + 0) * 32 + j] + a1 * w1[(4 * i4 + 1) * 32 + j] +
               a2 * w1[(4 * i4 + 2) * 32 + j] + a3 * w1[(4 * i4 + 3) * 32 + j];
    }
  }
  float z2[16];
#pragma unroll
  for (int j = 0; j < 16; ++j) z2[j] = b2s[j];
  for (int i = 0; i < 32; ++i) {
    float a = fmaxf(z1[i], 0.f);
#pragma unroll
    for (int j = 0; j < 16; ++j) z2[j] += a * w2[i * 16 + j];
  }
  float z3[8];
#pragma unroll
  for (int j = 0; j < 8; ++j) z3[j] = b3s[j];
  for (int i = 0; i < 16; ++i) {
    float a = fmaxf(z2[i], 0.f);
#pragma unroll
    for (int j = 0; j < 8; ++j) z3[j] += a * w3[i * 8 + j];
  }
  float z4[4];
#pragma unroll
  for (int j = 0; j < 4; ++j) z4[j] = b4s[j];
  for (int i = 0; i < 8; ++i) {
    float a = fmaxf(z3[i], 0.f);
#pragma unroll
    for (int j = 0; j < 4; ++j) z4[j] += a * w4[i * 4 + j];
  }
  float zo = obv;
#pragma unroll
  for (int i = 0; i < 4; ++i) zo += fmaxf(z4[i], 0.f) * wos[i];
  out[n] = 1.f / (1.f + __expf(-zo));
}

extern "C" void kernel_launch(void* const* d_in, const int* in_sizes, int n_in,
                              void* d_out, int out_size, void* d_ws, size_t ws_size,
                              hipStream_t stream) {
  const float* x  = (const float*)d_in[0];
  const int*   ei = (const int*)d_in[1];
  const float* W1 = (const float*)d_in[2];  const float* u1 = (const float*)d_in[3];
  const float* c1 = (const float*)d_in[4];  const float* b1 = (const float*)d_in[5];
  const float* W2 = (const float*)d_in[6];  const float* u2 = (const float*)d_in[7];
  const float* c2 = (const float*)d_in[8];  const float* b2 = (const float*)d_in[9];
  const float* W3 = (const float*)d_in[10]; const float* u3 = (const float*)d_in[11];
  const float* c3 = (const float*)d_in[12]; const float* b3 = (const float*)d_in[13];
  const float* gamma = (const float*)d_in[14]; const float* beta = (const float*)d_in[15];
  const float* lw1 = (const float*)d_in[16]; const float* lb1 = (const float*)d_in[17];
  const float* lw2 = (const float*)d_in[18]; const float* lb2 = (const float*)d_in[19];
  const float* lw3 = (const float*)d_in[20]; const float* lb3 = (const float*)d_in[21];
  const float* lw4 = (const float*)d_in[22]; const float* lb4 = (const float*)d_in[23];
  const float* ow  = (const float*)d_in[24]; const float* ob  = (const float*)d_in[25];
  float* out = (float*)d_out;

  float* t    = (float*)d_ws;                         // N*64   (layer-1 t)
  float* hA   = t + (size_t)NNODES * 64;              // N*64
  float* hB   = hA + (size_t)NNODES * 64;             // N*64
  float* s    = hB + (size_t)NNODES * 64;             // N*4
  float* sums = s + (size_t)NNODES * 4;               // 128
  float* Wk1  = sums + 128;                           // 4096
  float* Wk2  = Wk1 + 4096;                           // 2048
  float* Wk3  = Wk2 + 2048;                           // 8192
  int*   rowptr   = (int*)(Wk3 + 8192);               // N+1 (pad 8)
  int*   counts   = rowptr + NNODES + 8;              // N
  int*   blockSum = counts + NNODES;                  // 256
  u16*   col      = (u16*)(blockSum + 256);           // E u16
  u16*   rank     = col + NEDGES;                     // E u16

  hipMemsetAsync(counts, 0, NNODES * sizeof(int), stream);
  hipMemsetAsync(sums, 0, 128 * sizeof(float), stream);

  // ---- W transposes + CSR by dst ----
  prep_kernel<<<56, 256, 0, stream>>>(W1, W2, W3, Wk1, Wk2, Wk3);
  hist_kernel<<<(NEDGES + 255) / 256, 256, 0, stream>>>(ei, counts, rank);
  scanA_kernel<<<SCAN_BLOCKS, 256, 0, stream>>>(counts, rowptr, blockSum);
  scanBC_kernel<<<SCAN_BLOCKS, 256, 0, stream>>>(blockSum, rowptr);
  scatter_kernel<<<NSLICE * 8, 256, 0, stream>>>(ei, rowptr, rank, col);

  // ---- layer 1: 64 -> 16 (t-gather, fused softmax) ----
  ngemm_kernel<64, 64, 16><<<(NNODES + 63) / 64, 256, 0, stream>>>(x, Wk1, t);
  s_kernel<64><<<(NNODES * 4 + 255) / 256, 256, 0, stream>>>(x, u1, s);
  gather1_kernel<<<(NNODES + 31) / 32, 256, 0, stream>>>(rowptr, col, s, t, c1, b1, hA);

  // ---- layer 2: 16 -> 32 (fused gather+transform) ----
  s_kernel<16><<<(NNODES * 4 + 255) / 256, 256, 0, stream>>>(hA, u2, s);
  fusedG_kernel<16, 32, 16><<<(NNODES + 127) / 128, 256, 0, stream>>>(
      rowptr, col, s, hA, Wk2, c2, b2, hB);

  // ---- layer 3: 32 -> 64 (fused gather+transform) ----
  s_kernel<32><<<(NNODES * 4 + 255) / 256, 256, 0, stream>>>(hB, u3, s);
  fusedG_kernel<32, 64, 16><<<(NNODES + 63) / 64, 256, 0, stream>>>(
      rowptr, col, s, hB, Wk3, c3, b3, hA);

  // ---- BN stats + MLP head ----
  stats_kernel<<<256, 256, 0, stream>>>(hA, sums);
  mlp_kernel<<<(NNODES + 255) / 256, 256, 0, stream>>>(hA, sums, gamma, beta, lw1, lb1,
                                                       lw2, lb2, lw3, lb3, lw4, lb4,
                                                       ow, ob, out);
}

// Round 19
// 225.433 us; speedup vs baseline: 2.2927x; 1.0520x over previous
//
#include <hip/hip_runtime.h>

#define NNODES 50000
#define NEDGES 800000
#define SCAN_BLOCKS ((NNODES + 255) / 256)   // 196
#define NPART (NNODES / 8)                   // 6250 nodes per XCD partition
#define EPS 2048                             // edges per slice
#define NSLICE ((NEDGES + EPS - 1) / EPS)    // 391

typedef unsigned short u16;

// per-edge attention weights: softmax over heads of (s_src - s_dst + c)
__device__ __forceinline__ float4 softq(float4 ss, float4 sd, float4 c4) {
  float l0 = ss.x - sd.x + c4.x;
  float l1 = ss.y - sd.y + c4.y;
  float l2 = ss.z - sd.z + c4.z;
  float l3 = ss.w - sd.w + c4.w;
  float mx = fmaxf(fmaxf(l0, l1), fmaxf(l2, l3));
  float e0 = __expf(l0 - mx), e1 = __expf(l1 - mx);
  float e2 = __expf(l2 - mx), e3 = __expf(l3 - mx);
  float inv = 1.f / (e0 + e1 + e2 + e3);
  return make_float4(e0 * inv, e1 * inv, e2 * inv, e3 * inv);
}

__device__ __forceinline__ void fma4(float4& a, float q, float4 v) {
  a.x += q * v.x; a.y += q * v.y; a.z += q * v.z; a.w += q * v.w;
}
__device__ __forceinline__ float dot4(float4 a, float4 b) {
  return a.x * b.x + a.y * b.y + a.z * b.z + a.w * b.w;
}
__device__ __forceinline__ void st4T(float* ldsT, int k0, int NBp, int nl, float4 v) {
  ldsT[(k0 + 0) * NBp + nl] = v.x;
  ldsT[(k0 + 1) * NBp + nl] = v.y;
  ldsT[(k0 + 2) * NBp + nl] = v.z;
  ldsT[(k0 + 3) * NBp + nl] = v.w;
}
__device__ __forceinline__ float4 shfl4(float4 v, int e, int w) {
  return make_float4(__shfl(v.x, e, w), __shfl(v.y, e, w),
                     __shfl(v.z, e, w), __shfl(v.w, e, w));
}

// ---------------- hist + W-prep (merged): histogram over dst + rank (u16);
// blocks < 56 additionally transpose W1/W2/W3 into [k][o] rows. ----------------
__global__ __launch_bounds__(256) void histprep_kernel(const int* __restrict__ ei,
                                                       int* __restrict__ counts,
                                                       u16* __restrict__ rank,
                                                       const float* __restrict__ W1,
                                                       const float* __restrict__ W2,
                                                       const float* __restrict__ W3,
                                                       float* __restrict__ Wk1,
                                                       float* __restrict__ Wk2,
                                                       float* __restrict__ Wk3) {
  int i = blockIdx.x * 256 + threadIdx.x;
  if (i < 4096) {
    int f = i >> 6, j = i & 63;
    Wk1[i] = W1[f * 64 + ((j & 3) << 4) + (j >> 2)];
  } else if (i < 6144) {
    int i2 = i - 4096;
    int k = i2 >> 5, o = i2 & 31;
    int hh = k >> 4, f = k & 15;
    Wk2[i2] = W2[f * 128 + hh * 32 + o];
  } else if (i < 14336) {
    int i3 = i - 6144;
    int k = i3 >> 6, o = i3 & 63;
    int hh = k >> 5, f = k & 31;
    Wk3[i3] = W3[f * 256 + hh * 64 + o];
  }
  if (i < NEDGES) rank[i] = (u16)atomicAdd(&counts[ei[NEDGES + i]], 1);
}

__global__ __launch_bounds__(256) void scanA_kernel(const int* __restrict__ counts,
                                                    int* __restrict__ rowptr,
                                                    int* __restrict__ blockSum,
                                                    float* __restrict__ sums) {
  if (blockIdx.x == 0 && threadIdx.x < 128) sums[threadIdx.x] = 0.f;  // BN sums zero
  __shared__ int sm[256];
  int i = blockIdx.x * 256 + threadIdx.x;
  int v = (i < NNODES) ? counts[i] : 0;
  sm[threadIdx.x] = v;
  __syncthreads();
  for (int off = 1; off < 256; off <<= 1) {
    int x = (threadIdx.x >= off) ? sm[threadIdx.x - off] : 0;
    __syncthreads();
    sm[threadIdx.x] += x;
    __syncthreads();
  }
  if (i < NNODES) rowptr[i] = sm[threadIdx.x] - v;
  if (threadIdx.x == 255) blockSum[blockIdx.x] = sm[255];
}

// merged scanB+scanC
__global__ __launch_bounds__(256) void scanBC_kernel(const int* __restrict__ blockSum,
                                                     int* __restrict__ rowptr) {
  __shared__ int sm[256];
  int v = (threadIdx.x < SCAN_BLOCKS) ? blockSum[threadIdx.x] : 0;
  sm[threadIdx.x] = v;
  __syncthreads();
  for (int off = 1; off < 256; off <<= 1) {
    int x = (threadIdx.x >= off) ? sm[threadIdx.x - off] : 0;
    __syncthreads();
    sm[threadIdx.x] += x;
    __syncthreads();
  }
  int off = (blockIdx.x == 0) ? 0 : sm[blockIdx.x - 1];
  int i = blockIdx.x * 256 + threadIdx.x;
  if (i < NNODES) rowptr[i] += off;
  if (i == 0) rowptr[NNODES] = NEDGES;
}

// Atomic-free XCD-partitioned scatter (u16 payloads).
__global__ __launch_bounds__(256) void scatter_kernel(const int* __restrict__ ei,
                                                      const int* __restrict__ rowptr,
                                                      const u16* __restrict__ rank,
                                                      u16* __restrict__ col) {
  const int p = blockIdx.x & 7;
  const int sl = blockIdx.x >> 3;
  const int P0 = p * NPART;
  const int e1 = min((sl + 1) * EPS, NEDGES);
  for (int e = sl * EPS + threadIdx.x; e < e1; e += 256) {
    int dst = __builtin_nontemporal_load(&ei[NEDGES + e]);
    if ((unsigned)(dst - P0) < (unsigned)NPART) {
      int pos = rowptr[dst] + (int)__builtin_nontemporal_load(&rank[e]);
      col[pos] = (u16)__builtin_nontemporal_load(&ei[e]);
    }
  }
}

// ---------------- layer-1 t GEMM + fused s1 = x @ u1 ----------------
// Phase 1: stage x tile transposed; phase 2: t = x.Wk1 (1 ds_read + 16 FMA/k,
// W scalar path); phase 3: s1 from the SAME LDS tile (h = wave id, u1 scalar).
__global__ __launch_bounds__(256) void ngemm1_kernel(const float* __restrict__ A,
                                                     const float* __restrict__ Wk,
                                                     const float* __restrict__ u1,
                                                     float* __restrict__ t,
                                                     float* __restrict__ sOut) {
  constexpr int K = 64, OUTT = 64, MO = 16;
  constexpr int OG = OUTT / MO;   // 4
  constexpr int NB = 256 / OG;    // 64
  constexpr int NBp = NB + 1;
  __shared__ float ldsT[K * NBp];
  const int tid = threadIdx.x;
  const int nb0 = blockIdx.x * NB;
  for (int i = tid; i < NB * (K / 4); i += 256) {
    int r = i / (K / 4), kq = i - r * (K / 4);
    int n = nb0 + r;
    if (n >= NNODES) n = NNODES - 1;
    float4 v = ((const float4*)A)[n * (K / 4) + kq];
    st4T(ldsT, kq << 2, NBp, r, v);
  }
  __syncthreads();
  const int o0 = __builtin_amdgcn_readfirstlane(tid / NB) * MO;
  const int nl = tid & (NB - 1);
  const int n = nb0 + nl;
  float acc[MO];
#pragma unroll
  for (int m = 0; m < MO; ++m) acc[m] = 0.f;
#pragma unroll 4
  for (int k = 0; k < K; ++k) {
    float a = ldsT[k * NBp + nl];
    const float* wr = Wk + k * OUTT + o0;   // wave-uniform -> s_load
#pragma unroll
    for (int m = 0; m < MO; ++m) acc[m] += a * wr[m];
  }
  if (n < NNODES) {
#pragma unroll
    for (int m4 = 0; m4 < MO / 4; ++m4) {
      float4 v = make_float4(acc[m4 * 4 + 0], acc[m4 * 4 + 1],
                             acc[m4 * 4 + 2], acc[m4 * 4 + 3]);
      ((float4*)t)[n * (OUTT / 4) + (o0 >> 2) + m4] = v;
    }
  }
  // ---- phase 3: s1 (reuse LDS tile; no barrier needed, reads only) ----
  {
    const int hh = __builtin_amdgcn_readfirstlane(tid >> 6);  // wave id 0..3
    float accs = 0.f;
#pragma unroll 4
    for (int k = 0; k < K; ++k)
      accs += ldsT[k * NBp + nl] * u1[k * 4 + hh];            // u1 -> s_load
    if (n < NNODES) sOut[n * 4 + hh] = accs;
  }
}

// ---------------- fused g-gather + transform (layers 2/3) ----------------
template<int FIN, int OUTT, int MO>
__global__ __launch_bounds__(256) void fusedG_kernel(const int* __restrict__ rowptr,
                                                     const u16* __restrict__ col,
                                                     const float* __restrict__ s,
                                                     const float* __restrict__ x,
                                                     const float* __restrict__ Wk,
                                                     const float* __restrict__ cptr,
                                                     const float* __restrict__ bptr,
                                                     float* __restrict__ h) {
  constexpr int LPN = FIN / 8;        // lanes per node (2 or 4)
  constexpr int NB = 256 / LPN;       // nodes per block (128 or 64)
  constexpr int NBp = NB + 1;
  constexpr int K = 4 * FIN;
  constexpr int OG = OUTT / MO;       // must equal 256/NB (wave-uniform o0)
  static_assert(OG == 256 / NB, "geometry mismatch");
  __shared__ float ldsT[K * NBp];
  const int tid = threadIdx.x;
  const int nb0 = blockIdx.x * NB;
  const float4* sF4 = (const float4*)s;
  const float4* xF4 = (const float4*)x;

  // ---- phase 1: gather ----
  {
    const int lane = tid & (LPN - 1);
    const int sub = tid / LPN;
    int n = nb0 + sub;
    if (n >= NNODES) n = NNODES - 1;
    float4 c4 = *(const float4*)cptr;
    float mxc = fmaxf(fmaxf(c4.x, c4.y), fmaxf(c4.z, c4.w));
    float4 qsl = make_float4(__expf(c4.x - mxc), __expf(c4.y - mxc),
                             __expf(c4.z - mxc), __expf(c4.w - mxc));
    float sinv = 1.f / (qsl.x + qsl.y + qsl.z + qsl.w);
    qsl.x *= sinv; qsl.y *= sinv; qsl.z *= sinv; qsl.w *= sinv;
    float4 sd = sF4[n];
    const float4* xn = xF4 + n * (FIN / 4) + 2 * lane;
    float4 xa = xn[0], xb = xn[1];
    float4 g0a = make_float4(qsl.x * xa.x, qsl.x * xa.y, qsl.x * xa.z, qsl.x * xa.w);
    float4 g0b = make_float4(qsl.x * xb.x, qsl.x * xb.y, qsl.x * xb.z, qsl.x * xb.w);
    float4 g1a = make_float4(qsl.y * xa.x, qsl.y * xa.y, qsl.y * xa.z, qsl.y * xa.w);
    float4 g1b = make_float4(qsl.y * xb.x, qsl.y * xb.y, qsl.y * xb.z, qsl.y * xb.w);
    float4 g2a = make_float4(qsl.z * xa.x, qsl.z * xa.y, qsl.z * xa.z, qsl.z * xa.w);
    float4 g2b = make_float4(qsl.z * xb.x, qsl.z * xb.y, qsl.z * xb.z, qsl.z * xb.w);
    float4 g3a = make_float4(qsl.w * xa.x, qsl.w * xa.y, qsl.w * xa.z, qsl.w * xa.w);
    float4 g3b = make_float4(qsl.w * xb.x, qsl.w * xb.y, qsl.w * xb.z, qsl.w * xb.w);
    const int beg = rowptr[n], end = rowptr[n + 1];
    int idx = beg;
    for (; idx + LPN <= end; idx += LPN) {
      int myS = (int)col[idx + lane];
      float4 qL = softq(sF4[myS], sd, c4);
#pragma unroll
      for (int e = 0; e < LPN; ++e) {
        int srcE = __shfl(myS, e, LPN);
        float4 q = shfl4(qL, e, LPN);
        const float4* xr = xF4 + srcE * (FIN / 4) + 2 * lane;
        float4 x0a = xr[0], x0b = xr[1];
        fma4(g0a, q.x, x0a); fma4(g0b, q.x, x0b);
        fma4(g1a, q.y, x0a); fma4(g1b, q.y, x0b);
        fma4(g2a, q.z, x0a); fma4(g2b, q.z, x0b);
        fma4(g3a, q.w, x0a); fma4(g3b, q.w, x0b);
      }
    }
    for (; idx < end; ++idx) {
      int s0 = (int)col[idx];
      float4 qv = softq(sF4[s0], sd, c4);
      const float4* xr = xF4 + s0 * (FIN / 4) + 2 * lane;
      float4 x0a = xr[0], x0b = xr[1];
      fma4(g0a, qv.x, x0a); fma4(g0b, qv.x, x0b);
      fma4(g1a, qv.y, x0a); fma4(g1b, qv.y, x0b);
      fma4(g2a, qv.z, x0a); fma4(g2b, qv.z, x0b);
      fma4(g3a, qv.w, x0a); fma4(g3b, qv.w, x0b);
    }
    const int f0 = 8 * lane;
    st4T(ldsT, 0 * FIN + f0, NBp, sub, g0a); st4T(ldsT, 0 * FIN + f0 + 4, NBp, sub, g0b);
    st4T(ldsT, 1 * FIN + f0, NBp, sub, g1a); st4T(ldsT, 1 * FIN + f0 + 4, NBp, sub, g1b);
    st4T(ldsT, 2 * FIN + f0, NBp, sub, g2a); st4T(ldsT, 2 * FIN + f0 + 4, NBp, sub, g2b);
    st4T(ldsT, 3 * FIN + f0, NBp, sub, g3a); st4T(ldsT, 3 * FIN + f0 + 4, NBp, sub, g3b);
  }
  __syncthreads();

  // ---- phase 2: transform ----
  const int o0 = __builtin_amdgcn_readfirstlane(tid / NB) * MO;
  const int nl = tid & (NB - 1);
  const int n = nb0 + nl;
  float acc[MO];
#pragma unroll
  for (int m = 0; m < MO; ++m) acc[m] = 0.f;
#pragma unroll 4
  for (int k = 0; k < K; ++k) {
    float a = ldsT[k * NBp + nl];
    const float* wr = Wk + k * OUTT + o0;   // wave-uniform -> s_load
#pragma unroll
    for (int m = 0; m < MO; ++m) acc[m] += a * wr[m];
  }
  if (n < NNODES) {
    float sc = 1.f / (float)(rowptr[n + 1] - rowptr[n] + 1);
#pragma unroll
    for (int m4 = 0; m4 < MO / 4; ++m4) {
      float4 v;
      v.x = fmaxf(acc[m4 * 4 + 0] * sc + bptr[o0 + m4 * 4 + 0], 0.f);
      v.y = fmaxf(acc[m4 * 4 + 1] * sc + bptr[o0 + m4 * 4 + 1], 0.f);
      v.z = fmaxf(acc[m4 * 4 + 2] * sc + bptr[o0 + m4 * 4 + 2], 0.f);
      v.w = fmaxf(acc[m4 * 4 + 3] * sc + bptr[o0 + m4 * 4 + 3], 0.f);
      ((float4*)h)[n * (OUTT / 4) + (o0 >> 2) + m4] = v;
    }
  }
}

// ---------------- s = x @ u  ([N,4]) (layer-3 input only) ----------------
template<int FIN>
__global__ __launch_bounds__(256) void s_kernel(const float* __restrict__ x,
                                                const float* __restrict__ u,
                                                float* __restrict__ s) {
  int tid = blockIdx.x * 256 + threadIdx.x;
  int n = tid >> 2, h = tid & 3;
  if (n >= NNODES) return;
  const float4* xr = (const float4*)x + n * (FIN / 4);
  float acc = 0.f;
#pragma unroll
  for (int f4 = 0; f4 < FIN / 4; ++f4) {
    float4 xv = xr[f4];
    acc += xv.x * u[(4 * f4 + 0) * 4 + h] + xv.y * u[(4 * f4 + 1) * 4 + h] +
           xv.z * u[(4 * f4 + 2) * 4 + h] + xv.w * u[(4 * f4 + 3) * 4 + h];
  }
  s[tid] = acc;
}

// ---------------- layer-1 gather over t + fused s2 = h @ u2 ----------------
// 8 lanes/node; shfl-dedup softmax; epilogue: each lane's 2 outputs contribute
// to s2[n][0..3] via width-8 xor-reduce; lane 0 writes float4 to sOut (separate
// buffer -- writing the live s1 buffer would race with other blocks' reads).
__global__ __launch_bounds__(256) void gather1_kernel(const int* __restrict__ rowptr,
                                                      const u16* __restrict__ col,
                                                      const float* __restrict__ s,
                                                      const float* __restrict__ t,
                                                      const float* __restrict__ cptr,
                                                      const float* __restrict__ bptr,
                                                      const float* __restrict__ u2,
                                                      float* __restrict__ h,
                                                      float* __restrict__ sOut) {
  const int lane = threadIdx.x & 7;
  const int sub = threadIdx.x >> 3;
  const int n = blockIdx.x * 32 + sub;
  if (n >= NNODES) return;
  const float4* sF4 = (const float4*)s;
  const float4* tF4 = (const float4*)t;
  float4 c4 = *(const float4*)cptr;
  float mxc = fmaxf(fmaxf(c4.x, c4.y), fmaxf(c4.z, c4.w));
  float4 qs = make_float4(__expf(c4.x - mxc), __expf(c4.y - mxc),
                          __expf(c4.z - mxc), __expf(c4.w - mxc));
  float sinv = 1.f / (qs.x + qs.y + qs.z + qs.w);
  qs.x *= sinv; qs.y *= sinv; qs.z *= sinv; qs.w *= sinv;
  float4 sd = sF4[n];
  const float4* trow = tF4 + n * 16 + 2 * lane;
  float acc0 = dot4(qs, trow[0]);
  float acc1 = dot4(qs, trow[1]);
  const int beg = rowptr[n], end = rowptr[n + 1];
  int idx = beg;
  for (; idx + 8 <= end; idx += 8) {
    int myS = (int)col[idx + lane];
    float4 qL = softq(sF4[myS], sd, c4);
#pragma unroll
    for (int e = 0; e < 8; ++e) {
      int srcE = __shfl(myS, e, 8);
      float4 q = shfl4(qL, e, 8);
      const float4* tw = tF4 + srcE * 16 + 2 * lane;
      acc0 += dot4(q, tw[0]);
      acc1 += dot4(q, tw[1]);
    }
  }
  for (; idx < end; ++idx) {
    int src = (int)col[idx];
    float4 qv = softq(sF4[src], sd, c4);
    const float4* tw = tF4 + src * 16 + 2 * lane;
    acc0 += dot4(qv, tw[0]);
    acc1 += dot4(qv, tw[1]);
  }
  float d = 1.f / (float)(end - beg + 1);
  float v0 = fmaxf(acc0 * d + bptr[2 * lane + 0], 0.f);
  float v1 = fmaxf(acc1 * d + bptr[2 * lane + 1], 0.f);
  h[n * 16 + 2 * lane + 0] = v0;
  h[n * 16 + 2 * lane + 1] = v1;
  // fused s2: partial over this lane's 2 outputs, xor-reduce across 8 lanes
  float4 ua = ((const float4*)u2)[2 * lane];
  float4 ub = ((const float4*)u2)[2 * lane + 1];
  float4 p = make_float4(v0 * ua.x + v1 * ub.x, v0 * ua.y + v1 * ub.y,
                         v0 * ua.z + v1 * ub.z, v0 * ua.w + v1 * ub.w);
#pragma unroll
  for (int off = 1; off < 8; off <<= 1) {
    p.x += __shfl_xor(p.x, off);
    p.y += __shfl_xor(p.y, off);
    p.z += __shfl_xor(p.z, off);
    p.w += __shfl_xor(p.w, off);
  }
  if (lane == 0) ((float4*)sOut)[n] = p;
}

// ---------------- BN batch-stats over h3 [N,64] ----------------
__global__ __launch_bounds__(256) void stats_kernel(const float* __restrict__ h3,
                                                    float* __restrict__ sums) {
  const int o = threadIdx.x & 63;
  const int r = threadIdx.x >> 6;
  float accS = 0.f, accQ = 0.f;
  for (int base = blockIdx.x * 4; base < NNODES; base += gridDim.x * 4) {
    int n = base + r;
    if (n < NNODES) {
      float v = h3[n * 64 + o];
      accS += v;
      accQ += v * v;
    }
  }
  __shared__ float ls[256], lq[256];
  ls[threadIdx.x] = accS;
  lq[threadIdx.x] = accQ;
  __syncthreads();
  if (threadIdx.x < 64) {
    float a = ls[threadIdx.x] + ls[threadIdx.x + 64] + ls[threadIdx.x + 128] + ls[threadIdx.x + 192];
    float qq = lq[threadIdx.x] + lq[threadIdx.x + 64] + lq[threadIdx.x + 128] + lq[threadIdx.x + 192];
    atomicAdd(&sums[threadIdx.x], a);
    atomicAdd(&sums[64 + threadIdx.x], qq);
  }
}

// ---------------- BN + MLP head + sigmoid, one thread per node ----------------
__global__ __launch_bounds__(256) void mlp_kernel(
    const float* __restrict__ h3, const float* __restrict__ sums,
    const float* __restrict__ gamma, const float* __restrict__ beta,
    const float* __restrict__ lw1, const float* __restrict__ lb1,
    const float* __restrict__ lw2, const float* __restrict__ lb2,
    const float* __restrict__ lw3, const float* __restrict__ lb3,
    const float* __restrict__ lw4, const float* __restrict__ lb4,
    const float* __restrict__ ow, const float* __restrict__ ob,
    float* __restrict__ out) {
  __shared__ float w1[64 * 32], w2[32 * 16], w3[16 * 8], w4[8 * 4];
  __shared__ float b1s[32], b2s[16], b3s[8], b4s[4], wos[4];
  __shared__ float scale[64], shift[64];
  int tid = threadIdx.x;
  for (int i = tid; i < 64 * 32; i += 256) w1[i] = lw1[i];
  for (int i = tid; i < 32 * 16; i += 256) w2[i] = lw2[i];
  if (tid < 128) w3[tid] = lw3[tid];
  if (tid < 32) { w4[tid] = lw4[tid]; b1s[tid] = lb1[tid]; }
  if (tid < 16) b2s[tid] = lb2[tid];
  if (tid < 8) b3s[tid] = lb3[tid];
  if (tid < 4) { b4s[tid] = lb4[tid]; wos[tid] = ow[tid]; }
  if (tid < 64) {
    float mu = sums[tid] * (1.f / NNODES);
    float var = sums[64 + tid] * (1.f / NNODES) - mu * mu;
    float sc = rsqrtf(var + 1e-5f) * gamma[tid];
    scale[tid] = sc;
    shift[tid] = beta[tid] - mu * sc;
  }
  __syncthreads();
  int n = blockIdx.x * 256 + tid;
  if (n >= NNODES) return;
  float obv = ob[0];
  const float4* hr = (const float4*)h3 + n * 16;
  float z1[32];
#pragma unroll
  for (int j = 0; j < 32; ++j) z1[j] = b1s[j];
  for (int i4 = 0; i4 < 16; ++i4) {
    float4 hv = hr[i4];
    float a0 = hv.x * scale[4 * i4 + 0] + shift[4 * i4 + 0];
    float a1 = hv.y * scale[4 * i4 + 1] + shift[4 * i4 + 1];
    float a2 = hv.z * scale[4 * i4 + 2] + shift[4 * i4 + 2];
    float a3 = hv.w * scale[4 * i4 + 3] + shift[4 * i4 + 3];
#pragma unroll
    for (int j = 0; j < 32; ++j) {
      z1[j] += a0 * w1[(4 * i4 + 0) * 32 + j] + a1 * w1[(4 * i4 + 1) * 32 + j] +
               a2 * w1[(4 * i4 + 2) * 32 + j] + a3 * w1[(4 * i4 + 3) * 32 + j];
    }
  }
  float z2[16];
#pragma unroll
  for (int j = 0; j < 16; ++j) z2[j] = b2s[j];
  for (int i = 0; i < 32; ++i) {
    float a = fmaxf(z1[i], 0.f);
#pragma unroll
    for (int j = 0; j < 16; ++j) z2[j] += a * w2[i * 16 + j];
  }
  float z3[8];
#pragma unroll
  for (int j = 0; j < 8; ++j) z3[j] = b3s[j];
  for (int i = 0; i < 16; ++i) {
    float a = fmaxf(z2[i], 0.f);
#pragma unroll
    for (int j = 0; j < 8; ++j) z3[j] += a * w3[i * 8 + j];
  }
  float z4[4];
#pragma unroll
  for (int j = 0; j < 4; ++j) z4[j] = b4s[j];
  for (int i = 0; i < 8; ++i) {
    float a = fmaxf(z3[i], 0.f);
#pragma unroll
    for (int j = 0; j < 4; ++j) z4[j] += a * w4[i * 4 + j];
  }
  float zo = obv;
#pragma unroll
  for (int i = 0; i < 4; ++i) zo += fmaxf(z4[i], 0.f) * wos[i];
  out[n] = 1.f / (1.f + __expf(-zo));
}

extern "C" void kernel_launch(void* const* d_in, const int* in_sizes, int n_in,
                              void* d_out, int out_size, void* d_ws, size_t ws_size,
                              hipStream_t stream) {
  const float* x  = (const float*)d_in[0];
  const int*   ei = (const int*)d_in[1];
  const float* W1 = (const float*)d_in[2];  const float* u1 = (const float*)d_in[3];
  const float* c1 = (const float*)d_in[4];  const float* b1 = (const float*)d_in[5];
  const float* W2 = (const float*)d_in[6];  const float* u2 = (const float*)d_in[7];
  const float* c2 = (const float*)d_in[8];  const float* b2 = (const float*)d_in[9];
  const float* W3 = (const float*)d_in[10]; const float* u3 = (const float*)d_in[11];
  const float* c3 = (const float*)d_in[12]; const float* b3 = (const float*)d_in[13];
  const float* gamma = (const float*)d_in[14]; const float* beta = (const float*)d_in[15];
  const float* lw1 = (const float*)d_in[16]; const float* lb1 = (const float*)d_in[17];
  const float* lw2 = (const float*)d_in[18]; const float* lb2 = (const float*)d_in[19];
  const float* lw3 = (const float*)d_in[20]; const float* lb3 = (const float*)d_in[21];
  const float* lw4 = (const float*)d_in[22]; const float* lb4 = (const float*)d_in[23];
  const float* ow  = (const float*)d_in[24]; const float* ob  = (const float*)d_in[25];
  float* out = (float*)d_out;

  float* t    = (float*)d_ws;                         // N*64   (layer-1 t)
  float* hA   = t + (size_t)NNODES * 64;              // N*64
  float* hB   = hA + (size_t)NNODES * 64;             // N*64
  float* sA   = hB + (size_t)NNODES * 64;             // N*4  (s1, then s3)
  float* sB   = sA + (size_t)NNODES * 4;              // N*4  (s2)
  float* sums = sB + (size_t)NNODES * 4;              // 128
  float* Wk1  = sums + 128;                           // 4096
  float* Wk2  = Wk1 + 4096;                           // 2048
  float* Wk3  = Wk2 + 2048;                           // 8192
  int*   rowptr   = (int*)(Wk3 + 8192);               // N+1 (pad 8)
  int*   counts   = rowptr + NNODES + 8;              // N
  int*   blockSum = counts + NNODES;                  // 256
  u16*   col      = (u16*)(blockSum + 256);           // E u16
  u16*   rank     = col + NEDGES;                     // E u16

  hipMemsetAsync(counts, 0, NNODES * sizeof(int), stream);

  // ---- CSR by dst + W transposes (merged) ----
  histprep_kernel<<<(NEDGES + 255) / 256, 256, 0, stream>>>(ei, counts, rank,
                                                            W1, W2, W3, Wk1, Wk2, Wk3);
  scanA_kernel<<<SCAN_BLOCKS, 256, 0, stream>>>(counts, rowptr, blockSum, sums);
  scanBC_kernel<<<SCAN_BLOCKS, 256, 0, stream>>>(blockSum, rowptr);
  scatter_kernel<<<NSLICE * 8, 256, 0, stream>>>(ei, rowptr, rank, col);

  // ---- layer 1: 64 -> 16 (t-GEMM + s1 fused; gather + s2 fused) ----
  ngemm1_kernel<<<(NNODES + 63) / 64, 256, 0, stream>>>(x, Wk1, u1, t, sA);
  gather1_kernel<<<(NNODES + 31) / 32, 256, 0, stream>>>(rowptr, col, sA, t, c1, b1,
                                                         u2, hA, sB);

  // ---- layer 2: 16 -> 32 (fused gather+transform) ----
  fusedG_kernel<16, 32, 16><<<(NNODES + 127) / 128, 256, 0, stream>>>(
      rowptr, col, sB, hA, Wk2, c2, b2, hB);

  // ---- layer 3: 32 -> 64 (fused gather+transform) ----
  s_kernel<32><<<(NNODES * 4 + 255) / 256, 256, 0, stream>>>(hB, u3, sA);
  fusedG_kernel<32, 64, 16><<<(NNODES + 63) / 64, 256, 0, stream>>>(
      rowptr, col, sA, hB, Wk3, c3, b3, hA);

  // ---- BN stats + MLP head ----
  stats_kernel<<<256, 256, 0, stream>>>(hA, sums);
  mlp_kernel<<<(NNODES + 255) / 256, 256, 0, stream>>>(hA, sums, gamma, beta, lw1, lb1,
                                                       lw2, lb2, lw3, lb3, lw4, lb4,
                                                       ow, ob, out);
}

// Round 20
// 215.672 us; speedup vs baseline: 2.3965x; 1.0453x over previous
//
#include <hip/hip_runtime.h>

#define NNODES 50000
#define NEDGES 800000
#define SCAN_BLOCKS ((NNODES + 255) / 256)   // 196
#define NPART (NNODES / 8)                   // 6250 nodes per XCD partition
#define EPS 2048                             // edges per slice
#define NSLICE ((NEDGES + EPS - 1) / EPS)    // 391

typedef unsigned short u16;
typedef unsigned int u32;

// per-edge attention weights: softmax over heads of (s_src - s_dst + c)
__device__ __forceinline__ float4 softq(float4 ss, float4 sd, float4 c4) {
  float l0 = ss.x - sd.x + c4.x;
  float l1 = ss.y - sd.y + c4.y;
  float l2 = ss.z - sd.z + c4.z;
  float l3 = ss.w - sd.w + c4.w;
  float mx = fmaxf(fmaxf(l0, l1), fmaxf(l2, l3));
  float e0 = __expf(l0 - mx), e1 = __expf(l1 - mx);
  float e2 = __expf(l2 - mx), e3 = __expf(l3 - mx);
  float inv = 1.f / (e0 + e1 + e2 + e3);
  return make_float4(e0 * inv, e1 * inv, e2 * inv, e3 * inv);
}

__device__ __forceinline__ void fma4(float4& a, float q, float4 v) {
  a.x += q * v.x; a.y += q * v.y; a.z += q * v.z; a.w += q * v.w;
}
__device__ __forceinline__ float dot4(float4 a, float4 b) {
  return a.x * b.x + a.y * b.y + a.z * b.z + a.w * b.w;
}
__device__ __forceinline__ void st4T(float* ldsT, int k0, int NBp, int nl, float4 v) {
  ldsT[(k0 + 0) * NBp + nl] = v.x;
  ldsT[(k0 + 1) * NBp + nl] = v.y;
  ldsT[(k0 + 2) * NBp + nl] = v.z;
  ldsT[(k0 + 3) * NBp + nl] = v.w;
}
__device__ __forceinline__ float4 shfl4(float4 v, int e, int w) {
  return make_float4(__shfl(v.x, e, w), __shfl(v.y, e, w),
                     __shfl(v.z, e, w), __shfl(v.w, e, w));
}
// bf16 pack (RNE) / unpack via bit ops
__device__ __forceinline__ u32 bfpack(float a, float b) {
  u32 ua = __float_as_uint(a), ub = __float_as_uint(b);
  ua = (ua + 0x7FFFu + ((ua >> 16) & 1u)) >> 16;
  ub = (ub + 0x7FFFu + ((ub >> 16) & 1u)) & 0xFFFF0000u;
  return ua | ub;
}
__device__ __forceinline__ float bflo(u32 u) { return __uint_as_float(u << 16); }
__device__ __forceinline__ float bfhi(u32 u) { return __uint_as_float(u & 0xFFFF0000u); }

// ---------------- hist + W-prep (merged) ----------------
__global__ __launch_bounds__(256) void histprep_kernel(const int* __restrict__ ei,
                                                       int* __restrict__ counts,
                                                       u16* __restrict__ rank,
                                                       const float* __restrict__ W1,
                                                       const float* __restrict__ W2,
                                                       const float* __restrict__ W3,
                                                       float* __restrict__ Wk1,
                                                       float* __restrict__ Wk2,
                                                       float* __restrict__ Wk3) {
  int i = blockIdx.x * 256 + threadIdx.x;
  if (i < 4096) {
    int f = i >> 6, j = i & 63;
    Wk1[i] = W1[f * 64 + ((j & 3) << 4) + (j >> 2)];
  } else if (i < 6144) {
    int i2 = i - 4096;
    int k = i2 >> 5, o = i2 & 31;
    int hh = k >> 4, f = k & 15;
    Wk2[i2] = W2[f * 128 + hh * 32 + o];
  } else if (i < 14336) {
    int i3 = i - 6144;
    int k = i3 >> 6, o = i3 & 63;
    int hh = k >> 5, f = k & 31;
    Wk3[i3] = W3[f * 256 + hh * 64 + o];
  }
  if (i < NEDGES) rank[i] = (u16)atomicAdd(&counts[ei[NEDGES + i]], 1);
}

__global__ __launch_bounds__(256) void scanA_kernel(const int* __restrict__ counts,
                                                    int* __restrict__ rowptr,
                                                    int* __restrict__ blockSum,
                                                    float* __restrict__ sums) {
  if (blockIdx.x == 0 && threadIdx.x < 128) sums[threadIdx.x] = 0.f;
  __shared__ int sm[256];
  int i = blockIdx.x * 256 + threadIdx.x;
  int v = (i < NNODES) ? counts[i] : 0;
  sm[threadIdx.x] = v;
  __syncthreads();
  for (int off = 1; off < 256; off <<= 1) {
    int x = (threadIdx.x >= off) ? sm[threadIdx.x - off] : 0;
    __syncthreads();
    sm[threadIdx.x] += x;
    __syncthreads();
  }
  if (i < NNODES) rowptr[i] = sm[threadIdx.x] - v;
  if (threadIdx.x == 255) blockSum[blockIdx.x] = sm[255];
}

__global__ __launch_bounds__(256) void scanBC_kernel(const int* __restrict__ blockSum,
                                                     int* __restrict__ rowptr) {
  __shared__ int sm[256];
  int v = (threadIdx.x < SCAN_BLOCKS) ? blockSum[threadIdx.x] : 0;
  sm[threadIdx.x] = v;
  __syncthreads();
  for (int off = 1; off < 256; off <<= 1) {
    int x = (threadIdx.x >= off) ? sm[threadIdx.x - off] : 0;
    __syncthreads();
    sm[threadIdx.x] += x;
    __syncthreads();
  }
  int off = (blockIdx.x == 0) ? 0 : sm[blockIdx.x - 1];
  int i = blockIdx.x * 256 + threadIdx.x;
  if (i < NNODES) rowptr[i] += off;
  if (i == 0) rowptr[NNODES] = NEDGES;
}

// Atomic-free XCD-partitioned scatter (u16 payloads).
__global__ __launch_bounds__(256) void scatter_kernel(const int* __restrict__ ei,
                                                      const int* __restrict__ rowptr,
                                                      const u16* __restrict__ rank,
                                                      u16* __restrict__ col) {
  const int p = blockIdx.x & 7;
  const int sl = blockIdx.x >> 3;
  const int P0 = p * NPART;
  const int e1 = min((sl + 1) * EPS, NEDGES);
  for (int e = sl * EPS + threadIdx.x; e < e1; e += 256) {
    int dst = __builtin_nontemporal_load(&ei[NEDGES + e]);
    if ((unsigned)(dst - P0) < (unsigned)NPART) {
      int pos = rowptr[dst] + (int)__builtin_nontemporal_load(&rank[e]);
      col[pos] = (u16)__builtin_nontemporal_load(&ei[e]);
    }
  }
}

// ---------------- layer-1 t GEMM (bf16 t out) + fused s1 = x @ u1 ------------
__global__ __launch_bounds__(256) void ngemm1_kernel(const float* __restrict__ A,
                                                     const float* __restrict__ Wk,
                                                     const float* __restrict__ u1,
                                                     u16* __restrict__ tB,
                                                     float* __restrict__ sOut) {
  constexpr int K = 64, OUTT = 64, MO = 16;
  constexpr int OG = OUTT / MO;   // 4
  constexpr int NB = 256 / OG;    // 64
  constexpr int NBp = NB + 1;
  __shared__ float ldsT[K * NBp];
  const int tid = threadIdx.x;
  const int nb0 = blockIdx.x * NB;
  for (int i = tid; i < NB * (K / 4); i += 256) {
    int r = i / (K / 4), kq = i - r * (K / 4);
    int n = nb0 + r;
    if (n >= NNODES) n = NNODES - 1;
    float4 v = ((const float4*)A)[n * (K / 4) + kq];
    st4T(ldsT, kq << 2, NBp, r, v);
  }
  __syncthreads();
  const int o0 = __builtin_amdgcn_readfirstlane(tid / NB) * MO;
  const int nl = tid & (NB - 1);
  const int n = nb0 + nl;
  float acc[MO];
#pragma unroll
  for (int m = 0; m < MO; ++m) acc[m] = 0.f;
#pragma unroll 4
  for (int k = 0; k < K; ++k) {
    float a = ldsT[k * NBp + nl];
    const float* wr = Wk + k * OUTT + o0;   // wave-uniform -> s_load
#pragma unroll
    for (int m = 0; m < MO; ++m) acc[m] += a * wr[m];
  }
  if (n < NNODES) {
    uint4 w0, w1;
    w0.x = bfpack(acc[0], acc[1]);   w0.y = bfpack(acc[2], acc[3]);
    w0.z = bfpack(acc[4], acc[5]);   w0.w = bfpack(acc[6], acc[7]);
    w1.x = bfpack(acc[8], acc[9]);   w1.y = bfpack(acc[10], acc[11]);
    w1.z = bfpack(acc[12], acc[13]); w1.w = bfpack(acc[14], acc[15]);
    ((uint4*)tB)[n * 8 + (o0 >> 3) + 0] = w0;
    ((uint4*)tB)[n * 8 + (o0 >> 3) + 1] = w1;
  }
  // ---- phase 3: s1 (reuse LDS tile; reads only) ----
  {
    const int hh = __builtin_amdgcn_readfirstlane(tid >> 6);  // wave id 0..3
    float accs = 0.f;
#pragma unroll 4
    for (int k = 0; k < K; ++k)
      accs += ldsT[k * NBp + nl] * u1[k * 4 + hh];            // u1 -> s_load
    if (n < NNODES) sOut[n * 4 + hh] = accs;
  }
}

// ---------------- fused g-gather + transform (layers 2/3) ----------------
template<int FIN, int OUTT, int MO>
__global__ __launch_bounds__(256) void fusedG_kernel(const int* __restrict__ rowptr,
                                                     const u16* __restrict__ col,
                                                     const float* __restrict__ s,
                                                     const float* __restrict__ x,
                                                     const float* __restrict__ Wk,
                                                     const float* __restrict__ cptr,
                                                     const float* __restrict__ bptr,
                                                     float* __restrict__ h) {
  constexpr int LPN = FIN / 8;        // lanes per node (2 or 4)
  constexpr int NB = 256 / LPN;       // nodes per block (128 or 64)
  constexpr int NBp = NB + 1;
  constexpr int K = 4 * FIN;
  constexpr int OG = OUTT / MO;       // must equal 256/NB (wave-uniform o0)
  static_assert(OG == 256 / NB, "geometry mismatch");
  __shared__ float ldsT[K * NBp];
  const int tid = threadIdx.x;
  const int nb0 = blockIdx.x * NB;
  const float4* sF4 = (const float4*)s;
  const float4* xF4 = (const float4*)x;

  // ---- phase 1: gather ----
  {
    const int lane = tid & (LPN - 1);
    const int sub = tid / LPN;
    int n = nb0 + sub;
    if (n >= NNODES) n = NNODES - 1;
    float4 c4 = *(const float4*)cptr;
    float mxc = fmaxf(fmaxf(c4.x, c4.y), fmaxf(c4.z, c4.w));
    float4 qsl = make_float4(__expf(c4.x - mxc), __expf(c4.y - mxc),
                             __expf(c4.z - mxc), __expf(c4.w - mxc));
    float sinv = 1.f / (qsl.x + qsl.y + qsl.z + qsl.w);
    qsl.x *= sinv; qsl.y *= sinv; qsl.z *= sinv; qsl.w *= sinv;
    float4 sd = sF4[n];
    const float4* xn = xF4 + n * (FIN / 4) + 2 * lane;
    float4 xa = xn[0], xb = xn[1];
    float4 g0a = make_float4(qsl.x * xa.x, qsl.x * xa.y, qsl.x * xa.z, qsl.x * xa.w);
    float4 g0b = make_float4(qsl.x * xb.x, qsl.x * xb.y, qsl.x * xb.z, qsl.x * xb.w);
    float4 g1a = make_float4(qsl.y * xa.x, qsl.y * xa.y, qsl.y * xa.z, qsl.y * xa.w);
    float4 g1b = make_float4(qsl.y * xb.x, qsl.y * xb.y, qsl.y * xb.z, qsl.y * xb.w);
    float4 g2a = make_float4(qsl.z * xa.x, qsl.z * xa.y, qsl.z * xa.z, qsl.z * xa.w);
    float4 g2b = make_float4(qsl.z * xb.x, qsl.z * xb.y, qsl.z * xb.z, qsl.z * xb.w);
    float4 g3a = make_float4(qsl.w * xa.x, qsl.w * xa.y, qsl.w * xa.z, qsl.w * xa.w);
    float4 g3b = make_float4(qsl.w * xb.x, qsl.w * xb.y, qsl.w * xb.z, qsl.w * xb.w);
    const int beg = rowptr[n], end = rowptr[n + 1];
    int idx = beg;
    for (; idx + LPN <= end; idx += LPN) {
      int myS = (int)col[idx + lane];
      float4 qL = softq(sF4[myS], sd, c4);
#pragma unroll
      for (int e = 0; e < LPN; ++e) {
        int srcE = __shfl(myS, e, LPN);
        float4 q = shfl4(qL, e, LPN);
        const float4* xr = xF4 + srcE * (FIN / 4) + 2 * lane;
        float4 x0a = xr[0], x0b = xr[1];
        fma4(g0a, q.x, x0a); fma4(g0b, q.x, x0b);
        fma4(g1a, q.y, x0a); fma4(g1b, q.y, x0b);
        fma4(g2a, q.z, x0a); fma4(g2b, q.z, x0b);
        fma4(g3a, q.w, x0a); fma4(g3b, q.w, x0b);
      }
    }
    for (; idx < end; ++idx) {
      int s0 = (int)col[idx];
      float4 qv = softq(sF4[s0], sd, c4);
      const float4* xr = xF4 + s0 * (FIN / 4) + 2 * lane;
      float4 x0a = xr[0], x0b = xr[1];
      fma4(g0a, qv.x, x0a); fma4(g0b, qv.x, x0b);
      fma4(g1a, qv.y, x0a); fma4(g1b, qv.y, x0b);
      fma4(g2a, qv.z, x0a); fma4(g2b, qv.z, x0b);
      fma4(g3a, qv.w, x0a); fma4(g3b, qv.w, x0b);
    }
    const int f0 = 8 * lane;
    st4T(ldsT, 0 * FIN + f0, NBp, sub, g0a); st4T(ldsT, 0 * FIN + f0 + 4, NBp, sub, g0b);
    st4T(ldsT, 1 * FIN + f0, NBp, sub, g1a); st4T(ldsT, 1 * FIN + f0 + 4, NBp, sub, g1b);
    st4T(ldsT, 2 * FIN + f0, NBp, sub, g2a); st4T(ldsT, 2 * FIN + f0 + 4, NBp, sub, g2b);
    st4T(ldsT, 3 * FIN + f0, NBp, sub, g3a); st4T(ldsT, 3 * FIN + f0 + 4, NBp, sub, g3b);
  }
  __syncthreads();

  // ---- phase 2: transform ----
  const int o0 = __builtin_amdgcn_readfirstlane(tid / NB) * MO;
  const int nl = tid & (NB - 1);
  const int n = nb0 + nl;
  float acc[MO];
#pragma unroll
  for (int m = 0; m < MO; ++m) acc[m] = 0.f;
#pragma unroll 4
  for (int k = 0; k < K; ++k) {
    float a = ldsT[k * NBp + nl];
    const float* wr = Wk + k * OUTT + o0;   // wave-uniform -> s_load
#pragma unroll
    for (int m = 0; m < MO; ++m) acc[m] += a * wr[m];
  }
  if (n < NNODES) {
    float sc = 1.f / (float)(rowptr[n + 1] - rowptr[n] + 1);
#pragma unroll
    for (int m4 = 0; m4 < MO / 4; ++m4) {
      float4 v;
      v.x = fmaxf(acc[m4 * 4 + 0] * sc + bptr[o0 + m4 * 4 + 0], 0.f);
      v.y = fmaxf(acc[m4 * 4 + 1] * sc + bptr[o0 + m4 * 4 + 1], 0.f);
      v.z = fmaxf(acc[m4 * 4 + 2] * sc + bptr[o0 + m4 * 4 + 2], 0.f);
      v.w = fmaxf(acc[m4 * 4 + 3] * sc + bptr[o0 + m4 * 4 + 3], 0.f);
      ((float4*)h)[n * (OUTT / 4) + (o0 >> 2) + m4] = v;
    }
  }
}

// ---------------- s = x @ u  ([N,4]) (layer-3 input only) ----------------
template<int FIN>
__global__ __launch_bounds__(256) void s_kernel(const float* __restrict__ x,
                                                const float* __restrict__ u,
                                                float* __restrict__ s) {
  int tid = blockIdx.x * 256 + threadIdx.x;
  int n = tid >> 2, h = tid & 3;
  if (n >= NNODES) return;
  const float4* xr = (const float4*)x + n * (FIN / 4);
  float acc = 0.f;
#pragma unroll
  for (int f4 = 0; f4 < FIN / 4; ++f4) {
    float4 xv = xr[f4];
    acc += xv.x * u[(4 * f4 + 0) * 4 + h] + xv.y * u[(4 * f4 + 1) * 4 + h] +
           xv.z * u[(4 * f4 + 2) * 4 + h] + xv.w * u[(4 * f4 + 3) * 4 + h];
  }
  s[tid] = acc;
}

// ---------------- layer-1 gather over bf16 t + fused s2 = h @ u2 -------------
// 8 lanes/node; shfl-dedup softmax; per edge per lane ONE uint4 (8 bf16 = both
// owned outputs) instead of 2 float4 -- halves the dominant t-row traffic.
__global__ __launch_bounds__(256) void gather1_kernel(const int* __restrict__ rowptr,
                                                      const u16* __restrict__ col,
                                                      const float* __restrict__ s,
                                                      const u16* __restrict__ tB,
                                                      const float* __restrict__ cptr,
                                                      const float* __restrict__ bptr,
                                                      const float* __restrict__ u2,
                                                      float* __restrict__ h,
                                                      float* __restrict__ sOut) {
  const int lane = threadIdx.x & 7;
  const int sub = threadIdx.x >> 3;
  const int n = blockIdx.x * 32 + sub;
  if (n >= NNODES) return;
  const float4* sF4 = (const float4*)s;
  const uint4* tU4 = (const uint4*)tB;
  float4 c4 = *(const float4*)cptr;
  float mxc = fmaxf(fmaxf(c4.x, c4.y), fmaxf(c4.z, c4.w));
  float4 qs = make_float4(__expf(c4.x - mxc), __expf(c4.y - mxc),
                          __expf(c4.z - mxc), __expf(c4.w - mxc));
  float sinv = 1.f / (qs.x + qs.y + qs.z + qs.w);
  qs.x *= sinv; qs.y *= sinv; qs.z *= sinv; qs.w *= sinv;
  float4 sd = sF4[n];
  uint4 wn = tU4[n * 8 + lane];
  float acc0 = qs.x * bflo(wn.x) + qs.y * bfhi(wn.x) + qs.z * bflo(wn.y) + qs.w * bfhi(wn.y);
  float acc1 = qs.x * bflo(wn.z) + qs.y * bfhi(wn.z) + qs.z * bflo(wn.w) + qs.w * bfhi(wn.w);
  const int beg = rowptr[n], end = rowptr[n + 1];
  int idx = beg;
  for (; idx + 8 <= end; idx += 8) {
    int myS = (int)col[idx + lane];
    float4 qL = softq(sF4[myS], sd, c4);
#pragma unroll
    for (int e = 0; e < 8; ++e) {
      int srcE = __shfl(myS, e, 8);
      float4 q = shfl4(qL, e, 8);
      uint4 w = tU4[srcE * 8 + lane];
      acc0 += q.x * bflo(w.x) + q.y * bfhi(w.x) + q.z * bflo(w.y) + q.w * bfhi(w.y);
      acc1 += q.x * bflo(w.z) + q.y * bfhi(w.z) + q.z * bflo(w.w) + q.w * bfhi(w.w);
    }
  }
  for (; idx < end; ++idx) {
    int src = (int)col[idx];
    float4 qv = softq(sF4[src], sd, c4);
    uint4 w = tU4[src * 8 + lane];
    acc0 += qv.x * bflo(w.x) + qv.y * bfhi(w.x) + qv.z * bflo(w.y) + qv.w * bfhi(w.y);
    acc1 += qv.x * bflo(w.z) + qv.y * bfhi(w.z) + qv.z * bflo(w.w) + qv.w * bfhi(w.w);
  }
  float d = 1.f / (float)(end - beg + 1);
  float v0 = fmaxf(acc0 * d + bptr[2 * lane + 0], 0.f);
  float v1 = fmaxf(acc1 * d + bptr[2 * lane + 1], 0.f);
  h[n * 16 + 2 * lane + 0] = v0;
  h[n * 16 + 2 * lane + 1] = v1;
  // fused s2: partial over this lane's 2 outputs, xor-reduce across 8 lanes
  float4 ua = ((const float4*)u2)[2 * lane];
  float4 ub = ((const float4*)u2)[2 * lane + 1];
  float4 p = make_float4(v0 * ua.x + v1 * ub.x, v0 * ua.y + v1 * ub.y,
                         v0 * ua.z + v1 * ub.z, v0 * ua.w + v1 * ub.w);
#pragma unroll
  for (int off = 1; off < 8; off <<= 1) {
    p.x += __shfl_xor(p.x, off);
    p.y += __shfl_xor(p.y, off);
    p.z += __shfl_xor(p.z, off);
    p.w += __shfl_xor(p.w, off);
  }
  if (lane == 0) ((float4*)sOut)[n] = p;
}

// ---------------- BN batch-stats over h3 [N,64] ----------------
__global__ __launch_bounds__(256) void stats_kernel(const float* __restrict__ h3,
                                                    float* __restrict__ sums) {
  const int o = threadIdx.x & 63;
  const int r = threadIdx.x >> 6;
  float accS = 0.f, accQ = 0.f;
  for (int base = blockIdx.x * 4; base < NNODES; base += gridDim.x * 4) {
    int n = base + r;
    if (n < NNODES) {
      float v = h3[n * 64 + o];
      accS += v;
      accQ += v * v;
    }
  }
  __shared__ float ls[256], lq[256];
  ls[threadIdx.x] = accS;
  lq[threadIdx.x] = accQ;
  __syncthreads();
  if (threadIdx.x < 64) {
    float a = ls[threadIdx.x] + ls[threadIdx.x + 64] + ls[threadIdx.x + 128] + ls[threadIdx.x + 192];
    float qq = lq[threadIdx.x] + lq[threadIdx.x + 64] + lq[threadIdx.x + 128] + lq[threadIdx.x + 192];
    atomicAdd(&sums[threadIdx.x], a);
    atomicAdd(&sums[64 + threadIdx.x], qq);
  }
}

// ---------------- BN + MLP head + sigmoid, one thread per node ----------------
__global__ __launch_bounds__(256) void mlp_kernel(
    const float* __restrict__ h3, const float* __restrict__ sums,
    const float* __restrict__ gamma, const float* __restrict__ beta,
    const float* __restrict__ lw1, const float* __restrict__ lb1,
    const float* __restrict__ lw2, const float* __restrict__ lb2,
    const float* __restrict__ lw3, const float* __restrict__ lb3,
    const float* __restrict__ lw4, const float* __restrict__ lb4,
    const float* __restrict__ ow, const float* __restrict__ ob,
    float* __restrict__ out) {
  __shared__ float w1[64 * 32], w2[32 * 16], w3[16 * 8], w4[8 * 4];
  __shared__ float b1s[32], b2s[16], b3s[8], b4s[4], wos[4];
  __shared__ float scale[64], shift[64];
  int tid = threadIdx.x;
  for (int i = tid; i < 64 * 32; i += 256) w1[i] = lw1[i];
  for (int i = tid; i < 32 * 16; i += 256) w2[i] = lw2[i];
  if (tid < 128) w3[tid] = lw3[tid];
  if (tid < 32) { w4[tid] = lw4[tid]; b1s[tid] = lb1[tid]; }
  if (tid < 16) b2s[tid] = lb2[tid];
  if (tid < 8) b3s[tid] = lb3[tid];
  if (tid < 4) { b4s[tid] = lb4[tid]; wos[tid] = ow[tid]; }
  if (tid < 64) {
    float mu = sums[tid] * (1.f / NNODES);
    float var = sums[64 + tid] * (1.f / NNODES) - mu * mu;
    float sc = rsqrtf(var + 1e-5f) * gamma[tid];
    scale[tid] = sc;
    shift[tid] = beta[tid] - mu * sc;
  }
  __syncthreads();
  int n = blockIdx.x * 256 + tid;
  if (n >= NNODES) return;
  float obv = ob[0];
  const float4* hr = (const float4*)h3 + n * 16;
  float z1[32];
#pragma unroll
  for (int j = 0; j < 32; ++j) z1[j] = b1s[j];
  for (int i4 = 0; i4 < 16; ++i4) {
    float4 hv = hr[i4];
    float a0 = hv.x * scale[4 * i4 + 0] + shift[4 * i4 + 0];
    float a1 = hv.y * scale[4 * i4 + 1] + shift[4 * i4 + 1];
    float a2 = hv.z * scale[4 * i4 + 2] + shift[4 * i4 + 2];
    float a3 = hv.w * scale[4 * i4 + 3] + shift[4 * i4 + 3];
#pragma unroll
    for (int j = 0; j < 32; ++j) {
      z1[j] += a0 * w1[(4 * i4 + 0) * 32 + j] + a1 * w1[(4 * i4 + 1) * 32 + j] +
               a2 * w1[(4 * i4 + 2) * 32 + j] + a3 * w1[(4 * i4 + 3) * 32 + j];
    }
  }
  float z2[16];
#pragma unroll
  for (int j = 0; j < 16; ++j) z2[j] = b2s[j];
  for (int i = 0; i < 32; ++i) {
    float a = fmaxf(z1[i], 0.f);
#pragma unroll
    for (int j = 0; j < 16; ++j) z2[j] += a * w2[i * 16 + j];
  }
  float z3[8];
#pragma unroll
  for (int j = 0; j < 8; ++j) z3[j] = b3s[j];
  for (int i = 0; i < 16; ++i) {
    float a = fmaxf(z2[i], 0.f);
#pragma unroll
    for (int j = 0; j < 8; ++j) z3[j] += a * w3[i * 8 + j];
  }
  float z4[4];
#pragma unroll
  for (int j = 0; j < 4; ++j) z4[j] = b4s[j];
  for (int i = 0; i < 8; ++i) {
    float a = fmaxf(z3[i], 0.f);
#pragma unroll
    for (int j = 0; j < 4; ++j) z4[j] += a * w4[i * 4 + j];
  }
  float zo = obv;
#pragma unroll
  for (int i = 0; i < 4; ++i) zo += fmaxf(z4[i], 0.f) * wos[i];
  out[n] = 1.f / (1.f + __expf(-zo));
}

extern "C" void kernel_launch(void* const* d_in, const int* in_sizes, int n_in,
                              void* d_out, int out_size, void* d_ws, size_t ws_size,
                              hipStream_t stream) {
  const float* x  = (const float*)d_in[0];
  const int*   ei = (const int*)d_in[1];
  const float* W1 = (const float*)d_in[2];  const float* u1 = (const float*)d_in[3];
  const float* c1 = (const float*)d_in[4];  const float* b1 = (const float*)d_in[5];
  const float* W2 = (const float*)d_in[6];  const float* u2 = (const float*)d_in[7];
  const float* c2 = (const float*)d_in[8];  const float* b2 = (const float*)d_in[9];
  const float* W3 = (const float*)d_in[10]; const float* u3 = (const float*)d_in[11];
  const float* c3 = (const float*)d_in[12]; const float* b3 = (const float*)d_in[13];
  const float* gamma = (const float*)d_in[14]; const float* beta = (const float*)d_in[15];
  const float* lw1 = (const float*)d_in[16]; const float* lb1 = (const float*)d_in[17];
  const float* lw2 = (const float*)d_in[18]; const float* lb2 = (const float*)d_in[19];
  const float* lw3 = (const float*)d_in[20]; const float* lb3 = (const float*)d_in[21];
  const float* lw4 = (const float*)d_in[22]; const float* lb4 = (const float*)d_in[23];
  const float* ow  = (const float*)d_in[24]; const float* ob  = (const float*)d_in[25];
  float* out = (float*)d_out;

  u16*   tB   = (u16*)d_ws;                            // N*64 bf16 (N*32 floats)
  float* hA   = (float*)d_ws + (size_t)NNODES * 32;    // N*64
  float* hB   = hA + (size_t)NNODES * 64;              // N*64
  float* sA   = hB + (size_t)NNODES * 64;              // N*4  (s1, then s3)
  float* sB   = sA + (size_t)NNODES * 4;               // N*4  (s2)
  float* sums = sB + (size_t)NNODES * 4;               // 128
  float* Wk1  = sums + 128;                            // 4096
  float* Wk2  = Wk1 + 4096;                            // 2048
  float* Wk3  = Wk2 + 2048;                            // 8192
  int*   rowptr   = (int*)(Wk3 + 8192);                // N+1 (pad 8)
  int*   counts   = rowptr + NNODES + 8;               // N
  int*   blockSum = counts + NNODES;                   // 256
  u16*   col      = (u16*)(blockSum + 256);            // E u16
  u16*   rank     = col + NEDGES;                      // E u16

  hipMemsetAsync(counts, 0, NNODES * sizeof(int), stream);

  // ---- CSR by dst + W transposes (merged) ----
  histprep_kernel<<<(NEDGES + 255) / 256, 256, 0, stream>>>(ei, counts, rank,
                                                            W1, W2, W3, Wk1, Wk2, Wk3);
  scanA_kernel<<<SCAN_BLOCKS, 256, 0, stream>>>(counts, rowptr, blockSum, sums);
  scanBC_kernel<<<SCAN_BLOCKS, 256, 0, stream>>>(blockSum, rowptr);
  scatter_kernel<<<NSLICE * 8, 256, 0, stream>>>(ei, rowptr, rank, col);

  // ---- layer 1: 64 -> 16 (t-GEMM + s1 fused; gather + s2 fused) ----
  ngemm1_kernel<<<(NNODES + 63) / 64, 256, 0, stream>>>(x, Wk1, u1, tB, sA);
  gather1_kernel<<<(NNODES + 31) / 32, 256, 0, stream>>>(rowptr, col, sA, tB, c1, b1,
                                                         u2, hA, sB);

  // ---- layer 2: 16 -> 32 (fused gather+transform) ----
  fusedG_kernel<16, 32, 16><<<(NNODES + 127) / 128, 256, 0, stream>>>(
      rowptr, col, sB, hA, Wk2, c2, b2, hB);

  // ---- layer 3: 32 -> 64 (fused gather+transform) ----
  s_kernel<32><<<(NNODES * 4 + 255) / 256, 256, 0, stream>>>(hB, u3, sA);
  fusedG_kernel<32, 64, 16><<<(NNODES + 63) / 64, 256, 0, stream>>>(
      rowptr, col, sA, hB, Wk3, c3, b3, hA);

  // ---- BN stats + MLP head ----
  stats_kernel<<<256, 256, 0, stream>>>(hA, sums);
  mlp_kernel<<<(NNODES + 255) / 256, 256, 0, stream>>>(hA, sums, gamma, beta, lw1, lb1,
                                                       lw2, lb2, lw3, lb3, lw4, lb4,
                                                       ow, ob, out);
}

// Round 21
// 213.062 us; speedup vs baseline: 2.4258x; 1.0123x over previous
//
#include <hip/hip_runtime.h>

#define NNODES 50000
#define NEDGES 800000
#define SCAN_BLOCKS ((NNODES + 255) / 256)   // 196
#define NPART (NNODES / 8)                   // 6250 nodes per XCD partition
#define EPS 2048                             // edges per slice
#define NSLICE ((NEDGES + EPS - 1) / EPS)    // 391

typedef unsigned short u16;
typedef unsigned int u32;

// per-edge attention weights: softmax over heads of (s_src - s_dst + c)
__device__ __forceinline__ float4 softq(float4 ss, float4 sd, float4 c4) {
  float l0 = ss.x - sd.x + c4.x;
  float l1 = ss.y - sd.y + c4.y;
  float l2 = ss.z - sd.z + c4.z;
  float l3 = ss.w - sd.w + c4.w;
  float mx = fmaxf(fmaxf(l0, l1), fmaxf(l2, l3));
  float e0 = __expf(l0 - mx), e1 = __expf(l1 - mx);
  float e2 = __expf(l2 - mx), e3 = __expf(l3 - mx);
  float inv = 1.f / (e0 + e1 + e2 + e3);
  return make_float4(e0 * inv, e1 * inv, e2 * inv, e3 * inv);
}

__device__ __forceinline__ void fma4(float4& a, float q, float4 v) {
  a.x += q * v.x; a.y += q * v.y; a.z += q * v.z; a.w += q * v.w;
}
__device__ __forceinline__ float dot4(float4 a, float4 b) {
  return a.x * b.x + a.y * b.y + a.z * b.z + a.w * b.w;
}
__device__ __forceinline__ void st4T(float* ldsT, int k0, int NBp, int nl, float4 v) {
  ldsT[(k0 + 0) * NBp + nl] = v.x;
  ldsT[(k0 + 1) * NBp + nl] = v.y;
  ldsT[(k0 + 2) * NBp + nl] = v.z;
  ldsT[(k0 + 3) * NBp + nl] = v.w;
}
__device__ __forceinline__ float4 shfl4(float4 v, int e, int w) {
  return make_float4(__shfl(v.x, e, w), __shfl(v.y, e, w),
                     __shfl(v.z, e, w), __shfl(v.w, e, w));
}
// bf16 pack (RNE) / unpack via bit ops
__device__ __forceinline__ u32 bfpack(float a, float b) {
  u32 ua = __float_as_uint(a), ub = __float_as_uint(b);
  ua = (ua + 0x7FFFu + ((ua >> 16) & 1u)) >> 16;
  ub = (ub + 0x7FFFu + ((ub >> 16) & 1u)) & 0xFFFF0000u;
  return ua | ub;
}
__device__ __forceinline__ float bflo(u32 u) { return __uint_as_float(u << 16); }
__device__ __forceinline__ float bfhi(u32 u) { return __uint_as_float(u & 0xFFFF0000u); }

// ---------------- hist + W-prep (merged) ----------------
__global__ __launch_bounds__(256) void histprep_kernel(const int* __restrict__ ei,
                                                       int* __restrict__ counts,
                                                       u16* __restrict__ rank,
                                                       const float* __restrict__ W1,
                                                       const float* __restrict__ W2,
                                                       const float* __restrict__ W3,
                                                       float* __restrict__ Wk1,
                                                       float* __restrict__ Wk2,
                                                       float* __restrict__ Wk3) {
  int i = blockIdx.x * 256 + threadIdx.x;
  if (i < 4096) {
    int f = i >> 6, j = i & 63;
    Wk1[i] = W1[f * 64 + ((j & 3) << 4) + (j >> 2)];
  } else if (i < 6144) {
    int i2 = i - 4096;
    int k = i2 >> 5, o = i2 & 31;
    int hh = k >> 4, f = k & 15;
    Wk2[i2] = W2[f * 128 + hh * 32 + o];
  } else if (i < 14336) {
    int i3 = i - 6144;
    int k = i3 >> 6, o = i3 & 63;
    int hh = k >> 5, f = k & 31;
    Wk3[i3] = W3[f * 256 + hh * 64 + o];
  }
  if (i < NEDGES) rank[i] = (u16)atomicAdd(&counts[ei[NEDGES + i]], 1);
}

__global__ __launch_bounds__(256) void scanA_kernel(const int* __restrict__ counts,
                                                    int* __restrict__ rowptr,
                                                    int* __restrict__ blockSum,
                                                    float* __restrict__ sums) {
  if (blockIdx.x == 0 && threadIdx.x < 128) sums[threadIdx.x] = 0.f;
  __shared__ int sm[256];
  int i = blockIdx.x * 256 + threadIdx.x;
  int v = (i < NNODES) ? counts[i] : 0;
  sm[threadIdx.x] = v;
  __syncthreads();
  for (int off = 1; off < 256; off <<= 1) {
    int x = (threadIdx.x >= off) ? sm[threadIdx.x - off] : 0;
    __syncthreads();
    sm[threadIdx.x] += x;
    __syncthreads();
  }
  if (i < NNODES) rowptr[i] = sm[threadIdx.x] - v;
  if (threadIdx.x == 255) blockSum[blockIdx.x] = sm[255];
}

__global__ __launch_bounds__(256) void scanBC_kernel(const int* __restrict__ blockSum,
                                                     int* __restrict__ rowptr) {
  __shared__ int sm[256];
  int v = (threadIdx.x < SCAN_BLOCKS) ? blockSum[threadIdx.x] : 0;
  sm[threadIdx.x] = v;
  __syncthreads();
  for (int off = 1; off < 256; off <<= 1) {
    int x = (threadIdx.x >= off) ? sm[threadIdx.x - off] : 0;
    __syncthreads();
    sm[threadIdx.x] += x;
    __syncthreads();
  }
  int off = (blockIdx.x == 0) ? 0 : sm[blockIdx.x - 1];
  int i = blockIdx.x * 256 + threadIdx.x;
  if (i < NNODES) rowptr[i] += off;
  if (i == 0) rowptr[NNODES] = NEDGES;
}

// Atomic-free XCD-partitioned scatter (u16 payloads).
__global__ __launch_bounds__(256) void scatter_kernel(const int* __restrict__ ei,
                                                      const int* __restrict__ rowptr,
                                                      const u16* __restrict__ rank,
                                                      u16* __restrict__ col) {
  const int p = blockIdx.x & 7;
  const int sl = blockIdx.x >> 3;
  const int P0 = p * NPART;
  const int e1 = min((sl + 1) * EPS, NEDGES);
  for (int e = sl * EPS + threadIdx.x; e < e1; e += 256) {
    int dst = __builtin_nontemporal_load(&ei[NEDGES + e]);
    if ((unsigned)(dst - P0) < (unsigned)NPART) {
      int pos = rowptr[dst] + (int)__builtin_nontemporal_load(&rank[e]);
      col[pos] = (u16)__builtin_nontemporal_load(&ei[e]);
    }
  }
}

// ---------------- layer-1 t GEMM (bf16 t out) + fused s1 = x @ u1 ------------
__global__ __launch_bounds__(256) void ngemm1_kernel(const float* __restrict__ A,
                                                     const float* __restrict__ Wk,
                                                     const float* __restrict__ u1,
                                                     u16* __restrict__ tB,
                                                     float* __restrict__ sOut) {
  constexpr int K = 64, OUTT = 64, MO = 16;
  constexpr int OG = OUTT / MO;   // 4
  constexpr int NB = 256 / OG;    // 64
  constexpr int NBp = NB + 1;
  __shared__ float ldsT[K * NBp];
  const int tid = threadIdx.x;
  const int nb0 = blockIdx.x * NB;
  for (int i = tid; i < NB * (K / 4); i += 256) {
    int r = i / (K / 4), kq = i - r * (K / 4);
    int n = nb0 + r;
    if (n >= NNODES) n = NNODES - 1;
    float4 v = ((const float4*)A)[n * (K / 4) + kq];
    st4T(ldsT, kq << 2, NBp, r, v);
  }
  __syncthreads();
  const int o0 = __builtin_amdgcn_readfirstlane(tid / NB) * MO;
  const int nl = tid & (NB - 1);
  const int n = nb0 + nl;
  float acc[MO];
#pragma unroll
  for (int m = 0; m < MO; ++m) acc[m] = 0.f;
#pragma unroll 4
  for (int k = 0; k < K; ++k) {
    float a = ldsT[k * NBp + nl];
    const float* wr = Wk + k * OUTT + o0;   // wave-uniform -> s_load
#pragma unroll
    for (int m = 0; m < MO; ++m) acc[m] += a * wr[m];
  }
  if (n < NNODES) {
    uint4 w0, w1;
    w0.x = bfpack(acc[0], acc[1]);   w0.y = bfpack(acc[2], acc[3]);
    w0.z = bfpack(acc[4], acc[5]);   w0.w = bfpack(acc[6], acc[7]);
    w1.x = bfpack(acc[8], acc[9]);   w1.y = bfpack(acc[10], acc[11]);
    w1.z = bfpack(acc[12], acc[13]); w1.w = bfpack(acc[14], acc[15]);
    ((uint4*)tB)[n * 8 + (o0 >> 3) + 0] = w0;
    ((uint4*)tB)[n * 8 + (o0 >> 3) + 1] = w1;
  }
  // ---- phase 3: s1 (reuse LDS tile; reads only) ----
  {
    const int hh = __builtin_amdgcn_readfirstlane(tid >> 6);  // wave id 0..3
    float accs = 0.f;
#pragma unroll 4
    for (int k = 0; k < K; ++k)
      accs += ldsT[k * NBp + nl] * u1[k * 4 + hh];            // u1 -> s_load
    if (n < NNODES) sOut[n * 4 + hh] = accs;
  }
}

// ---------------- fused g-gather + transform (layers 2/3) ----------------
// XBF: gather input x is bf16-packed ([N][FIN] bf16); OBF: output h bf16-packed.
template<int FIN, int OUTT, int MO, bool XBF, bool OBF>
__global__ __launch_bounds__(256) void fusedG_kernel(const int* __restrict__ rowptr,
                                                     const u16* __restrict__ col,
                                                     const float* __restrict__ s,
                                                     const void* __restrict__ xIn,
                                                     const float* __restrict__ Wk,
                                                     const float* __restrict__ cptr,
                                                     const float* __restrict__ bptr,
                                                     void* __restrict__ hOut) {
  constexpr int LPN = FIN / 8;        // lanes per node (2 or 4)
  constexpr int NB = 256 / LPN;       // nodes per block (128 or 64)
  constexpr int NBp = NB + 1;
  constexpr int K = 4 * FIN;
  constexpr int OG = OUTT / MO;       // must equal 256/NB (wave-uniform o0)
  static_assert(OG == 256 / NB, "geometry mismatch");
  __shared__ float ldsT[K * NBp];
  const int tid = threadIdx.x;
  const int nb0 = blockIdx.x * NB;
  const float4* sF4 = (const float4*)s;

  // ---- phase 1: gather ----
  {
    const int lane = tid & (LPN - 1);
    const int sub = tid / LPN;
    int n = nb0 + sub;
    if (n >= NNODES) n = NNODES - 1;
    float4 c4 = *(const float4*)cptr;
    float mxc = fmaxf(fmaxf(c4.x, c4.y), fmaxf(c4.z, c4.w));
    float4 qsl = make_float4(__expf(c4.x - mxc), __expf(c4.y - mxc),
                             __expf(c4.z - mxc), __expf(c4.w - mxc));
    float sinv = 1.f / (qsl.x + qsl.y + qsl.z + qsl.w);
    qsl.x *= sinv; qsl.y *= sinv; qsl.z *= sinv; qsl.w *= sinv;
    float4 sd = sF4[n];
    float4 xa, xb;
    if (XBF) {
      uint4 w = ((const uint4*)xIn)[n * (FIN / 8) + lane];
      xa = make_float4(bflo(w.x), bfhi(w.x), bflo(w.y), bfhi(w.y));
      xb = make_float4(bflo(w.z), bfhi(w.z), bflo(w.w), bfhi(w.w));
    } else {
      const float4* xn = (const float4*)xIn + n * (FIN / 4) + 2 * lane;
      xa = xn[0]; xb = xn[1];
    }
    float4 g0a = make_float4(qsl.x * xa.x, qsl.x * xa.y, qsl.x * xa.z, qsl.x * xa.w);
    float4 g0b = make_float4(qsl.x * xb.x, qsl.x * xb.y, qsl.x * xb.z, qsl.x * xb.w);
    float4 g1a = make_float4(qsl.y * xa.x, qsl.y * xa.y, qsl.y * xa.z, qsl.y * xa.w);
    float4 g1b = make_float4(qsl.y * xb.x, qsl.y * xb.y, qsl.y * xb.z, qsl.y * xb.w);
    float4 g2a = make_float4(qsl.z * xa.x, qsl.z * xa.y, qsl.z * xa.z, qsl.z * xa.w);
    float4 g2b = make_float4(qsl.z * xb.x, qsl.z * xb.y, qsl.z * xb.z, qsl.z * xb.w);
    float4 g3a = make_float4(qsl.w * xa.x, qsl.w * xa.y, qsl.w * xa.z, qsl.w * xa.w);
    float4 g3b = make_float4(qsl.w * xb.x, qsl.w * xb.y, qsl.w * xb.z, qsl.w * xb.w);
    const int beg = rowptr[n], end = rowptr[n + 1];
    int idx = beg;
    for (; idx + LPN <= end; idx += LPN) {
      int myS = (int)col[idx + lane];
      float4 qL = softq(sF4[myS], sd, c4);
#pragma unroll
      for (int e = 0; e < LPN; ++e) {
        int srcE = __shfl(myS, e, LPN);
        float4 q = shfl4(qL, e, LPN);
        float4 x0a, x0b;
        if (XBF) {
          uint4 w = ((const uint4*)xIn)[srcE * (FIN / 8) + lane];
          x0a = make_float4(bflo(w.x), bfhi(w.x), bflo(w.y), bfhi(w.y));
          x0b = make_float4(bflo(w.z), bfhi(w.z), bflo(w.w), bfhi(w.w));
        } else {
          const float4* xr = (const float4*)xIn + srcE * (FIN / 4) + 2 * lane;
          x0a = xr[0]; x0b = xr[1];
        }
        fma4(g0a, q.x, x0a); fma4(g0b, q.x, x0b);
        fma4(g1a, q.y, x0a); fma4(g1b, q.y, x0b);
        fma4(g2a, q.z, x0a); fma4(g2b, q.z, x0b);
        fma4(g3a, q.w, x0a); fma4(g3b, q.w, x0b);
      }
    }
    for (; idx < end; ++idx) {
      int s0 = (int)col[idx];
      float4 qv = softq(sF4[s0], sd, c4);
      float4 x0a, x0b;
      if (XBF) {
        uint4 w = ((const uint4*)xIn)[s0 * (FIN / 8) + lane];
        x0a = make_float4(bflo(w.x), bfhi(w.x), bflo(w.y), bfhi(w.y));
        x0b = make_float4(bflo(w.z), bfhi(w.z), bflo(w.w), bfhi(w.w));
      } else {
        const float4* xr = (const float4*)xIn + s0 * (FIN / 4) + 2 * lane;
        x0a = xr[0]; x0b = xr[1];
      }
      fma4(g0a, qv.x, x0a); fma4(g0b, qv.x, x0b);
      fma4(g1a, qv.y, x0a); fma4(g1b, qv.y, x0b);
      fma4(g2a, qv.z, x0a); fma4(g2b, qv.z, x0b);
      fma4(g3a, qv.w, x0a); fma4(g3b, qv.w, x0b);
    }
    const int f0 = 8 * lane;
    st4T(ldsT, 0 * FIN + f0, NBp, sub, g0a); st4T(ldsT, 0 * FIN + f0 + 4, NBp, sub, g0b);
    st4T(ldsT, 1 * FIN + f0, NBp, sub, g1a); st4T(ldsT, 1 * FIN + f0 + 4, NBp, sub, g1b);
    st4T(ldsT, 2 * FIN + f0, NBp, sub, g2a); st4T(ldsT, 2 * FIN + f0 + 4, NBp, sub, g2b);
    st4T(ldsT, 3 * FIN + f0, NBp, sub, g3a); st4T(ldsT, 3 * FIN + f0 + 4, NBp, sub, g3b);
  }
  __syncthreads();

  // ---- phase 2: transform ----
  const int o0 = __builtin_amdgcn_readfirstlane(tid / NB) * MO;
  const int nl = tid & (NB - 1);
  const int n = nb0 + nl;
  float acc[MO];
#pragma unroll
  for (int m = 0; m < MO; ++m) acc[m] = 0.f;
#pragma unroll 4
  for (int k = 0; k < K; ++k) {
    float a = ldsT[k * NBp + nl];
    const float* wr = Wk + k * OUTT + o0;   // wave-uniform -> s_load
#pragma unroll
    for (int m = 0; m < MO; ++m) acc[m] += a * wr[m];
  }
  if (n < NNODES) {
    float sc = 1.f / (float)(rowptr[n + 1] - rowptr[n] + 1);
#pragma unroll
    for (int m = 0; m < MO; ++m)
      acc[m] = fmaxf(acc[m] * sc + bptr[o0 + m], 0.f);   // in-place epilogue
    if (OBF) {
      uint4 w0, w1;
      w0.x = bfpack(acc[0], acc[1]);   w0.y = bfpack(acc[2], acc[3]);
      w0.z = bfpack(acc[4], acc[5]);   w0.w = bfpack(acc[6], acc[7]);
      w1.x = bfpack(acc[8], acc[9]);   w1.y = bfpack(acc[10], acc[11]);
      w1.z = bfpack(acc[12], acc[13]); w1.w = bfpack(acc[14], acc[15]);
      ((uint4*)hOut)[n * (OUTT / 8) + (o0 >> 3) + 0] = w0;
      ((uint4*)hOut)[n * (OUTT / 8) + (o0 >> 3) + 1] = w1;
    } else {
#pragma unroll
      for (int m4 = 0; m4 < MO / 4; ++m4) {
        float4 v = make_float4(acc[m4 * 4 + 0], acc[m4 * 4 + 1],
                               acc[m4 * 4 + 2], acc[m4 * 4 + 3]);
        ((float4*)hOut)[n * (OUTT / 4) + (o0 >> 2) + m4] = v;
      }
    }
  }
}

// ---------------- s = x @ u from bf16-packed x ([N,4]) ----------------
template<int FIN>
__global__ __launch_bounds__(256) void s_kernel_bf(const u16* __restrict__ xB,
                                                   const float* __restrict__ u,
                                                   float* __restrict__ s) {
  int tid = blockIdx.x * 256 + threadIdx.x;
  int n = tid >> 2, h = tid & 3;
  if (n >= NNODES) return;
  const uint4* xr = (const uint4*)xB + n * (FIN / 8);
  float acc = 0.f;
#pragma unroll
  for (int q8 = 0; q8 < FIN / 8; ++q8) {
    uint4 w = xr[q8];
    int f0 = q8 * 8;
    acc += bflo(w.x) * u[(f0 + 0) * 4 + h] + bfhi(w.x) * u[(f0 + 1) * 4 + h] +
           bflo(w.y) * u[(f0 + 2) * 4 + h] + bfhi(w.y) * u[(f0 + 3) * 4 + h] +
           bflo(w.z) * u[(f0 + 4) * 4 + h] + bfhi(w.z) * u[(f0 + 5) * 4 + h] +
           bflo(w.w) * u[(f0 + 6) * 4 + h] + bfhi(w.w) * u[(f0 + 7) * 4 + h];
  }
  s[tid] = acc;
}

// ---------------- layer-1 gather over bf16 t + fused s2; bf16 h1 out ---------
__global__ __launch_bounds__(256) void gather1_kernel(const int* __restrict__ rowptr,
                                                      const u16* __restrict__ col,
                                                      const float* __restrict__ s,
                                                      const u16* __restrict__ tB,
                                                      const float* __restrict__ cptr,
                                                      const float* __restrict__ bptr,
                                                      const float* __restrict__ u2,
                                                      u16* __restrict__ h1B,
                                                      float* __restrict__ sOut) {
  const int lane = threadIdx.x & 7;
  const int sub = threadIdx.x >> 3;
  const int n = blockIdx.x * 32 + sub;
  if (n >= NNODES) return;
  const float4* sF4 = (const float4*)s;
  const uint4* tU4 = (const uint4*)tB;
  float4 c4 = *(const float4*)cptr;
  float mxc = fmaxf(fmaxf(c4.x, c4.y), fmaxf(c4.z, c4.w));
  float4 qs = make_float4(__expf(c4.x - mxc), __expf(c4.y - mxc),
                          __expf(c4.z - mxc), __expf(c4.w - mxc));
  float sinv = 1.f / (qs.x + qs.y + qs.z + qs.w);
  qs.x *= sinv; qs.y *= sinv; qs.z *= sinv; qs.w *= sinv;
  float4 sd = sF4[n];
  uint4 wn = tU4[n * 8 + lane];
  float acc0 = qs.x * bflo(wn.x) + qs.y * bfhi(wn.x) + qs.z * bflo(wn.y) + qs.w * bfhi(wn.y);
  float acc1 = qs.x * bflo(wn.z) + qs.y * bfhi(wn.z) + qs.z * bflo(wn.w) + qs.w * bfhi(wn.w);
  const int beg = rowptr[n], end = rowptr[n + 1];
  int idx = beg;
  for (; idx + 8 <= end; idx += 8) {
    int myS = (int)col[idx + lane];
    float4 qL = softq(sF4[myS], sd, c4);
#pragma unroll
    for (int e = 0; e < 8; ++e) {
      int srcE = __shfl(myS, e, 8);
      float4 q = shfl4(qL, e, 8);
      uint4 w = tU4[srcE * 8 + lane];
      acc0 += q.x * bflo(w.x) + q.y * bfhi(w.x) + q.z * bflo(w.y) + q.w * bfhi(w.y);
      acc1 += q.x * bflo(w.z) + q.y * bfhi(w.z) + q.z * bflo(w.w) + q.w * bfhi(w.w);
    }
  }
  for (; idx < end; ++idx) {
    int src = (int)col[idx];
    float4 qv = softq(sF4[src], sd, c4);
    uint4 w = tU4[src * 8 + lane];
    acc0 += qv.x * bflo(w.x) + qv.y * bfhi(w.x) + qv.z * bflo(w.y) + qv.w * bfhi(w.y);
    acc1 += qv.x * bflo(w.z) + qv.y * bfhi(w.z) + qv.z * bflo(w.w) + qv.w * bfhi(w.w);
  }
  float d = 1.f / (float)(end - beg + 1);
  float v0 = fmaxf(acc0 * d + bptr[2 * lane + 0], 0.f);
  float v1 = fmaxf(acc1 * d + bptr[2 * lane + 1], 0.f);
  ((u32*)h1B)[n * 8 + lane] = bfpack(v0, v1);
  // fused s2: partial over this lane's 2 outputs, xor-reduce across 8 lanes
  float4 ua = ((const float4*)u2)[2 * lane];
  float4 ub = ((const float4*)u2)[2 * lane + 1];
  float4 p = make_float4(v0 * ua.x + v1 * ub.x, v0 * ua.y + v1 * ub.y,
                         v0 * ua.z + v1 * ub.z, v0 * ua.w + v1 * ub.w);
#pragma unroll
  for (int off = 1; off < 8; off <<= 1) {
    p.x += __shfl_xor(p.x, off);
    p.y += __shfl_xor(p.y, off);
    p.z += __shfl_xor(p.z, off);
    p.w += __shfl_xor(p.w, off);
  }
  if (lane == 0) ((float4*)sOut)[n] = p;
}

// ---------------- BN batch-stats over h3 [N,64] ----------------
__global__ __launch_bounds__(256) void stats_kernel(const float* __restrict__ h3,
                                                    float* __restrict__ sums) {
  const int o = threadIdx.x & 63;
  const int r = threadIdx.x >> 6;
  float accS = 0.f, accQ = 0.f;
  for (int base = blockIdx.x * 4; base < NNODES; base += gridDim.x * 4) {
    int n = base + r;
    if (n < NNODES) {
      float v = h3[n * 64 + o];
      accS += v;
      accQ += v * v;
    }
  }
  __shared__ float ls[256], lq[256];
  ls[threadIdx.x] = accS;
  lq[threadIdx.x] = accQ;
  __syncthreads();
  if (threadIdx.x < 64) {
    float a = ls[threadIdx.x] + ls[threadIdx.x + 64] + ls[threadIdx.x + 128] + ls[threadIdx.x + 192];
    float qq = lq[threadIdx.x] + lq[threadIdx.x + 64] + lq[threadIdx.x + 128] + lq[threadIdx.x + 192];
    atomicAdd(&sums[threadIdx.x], a);
    atomicAdd(&sums[64 + threadIdx.x], qq);
  }
}

// ---------------- BN + MLP head + sigmoid, one thread per node ----------------
__global__ __launch_bounds__(256) void mlp_kernel(
    const float* __restrict__ h3, const float* __restrict__ sums,
    const float* __restrict__ gamma, const float* __restrict__ beta,
    const float* __restrict__ lw1, const float* __restrict__ lb1,
    const float* __restrict__ lw2, const float* __restrict__ lb2,
    const float* __restrict__ lw3, const float* __restrict__ lb3,
    const float* __restrict__ lw4, const float* __restrict__ lb4,
    const float* __restrict__ ow, const float* __restrict__ ob,
    float* __restrict__ out) {
  __shared__ float w1[64 * 32], w2[32 * 16], w3[16 * 8], w4[8 * 4];
  __shared__ float b1s[32], b2s[16], b3s[8], b4s[4], wos[4];
  __shared__ float scale[64], shift[64];
  int tid = threadIdx.x;
  for (int i = tid; i < 64 * 32; i += 256) w1[i] = lw1[i];
  for (int i = tid; i < 32 * 16; i += 256) w2[i] = lw2[i];
  if (tid < 128) w3[tid] = lw3[tid];
  if (tid < 32) { w4[tid] = lw4[tid]; b1s[tid] = lb1[tid]; }
  if (tid < 16) b2s[tid] = lb2[tid];
  if (tid < 8) b3s[tid] = lb3[tid];
  if (tid < 4) { b4s[tid] = lb4[tid]; wos[tid] = ow[tid]; }
  if (tid < 64) {
    float mu = sums[tid] * (1.f / NNODES);
    float var = sums[64 + tid] * (1.f / NNODES) - mu * mu;
    float sc = rsqrtf(var + 1e-5f) * gamma[tid];
    scale[tid] = sc;
    shift[tid] = beta[tid] - mu * sc;
  }
  __syncthreads();
  int n = blockIdx.x * 256 + tid;
  if (n >= NNODES) return;
  float obv = ob[0];
  const float4* hr = (const float4*)h3 + n * 16;
  float z1[32];
#pragma unroll
  for (int j = 0; j < 32; ++j) z1[j] = b1s[j];
  for (int i4 = 0; i4 < 16; ++i4) {
    float4 hv = hr[i4];
    float a0 = hv.x * scale[4 * i4 + 0] + shift[4 * i4 + 0];
    float a1 = hv.y * scale[4 * i4 + 1] + shift[4 * i4 + 1];
    float a2 = hv.z * scale[4 * i4 + 2] + shift[4 * i4 + 2];
    float a3 = hv.w * scale[4 * i4 + 3] + shift[4 * i4 + 3];
#pragma unroll
    for (int j = 0; j < 32; ++j) {
      z1[j] += a0 * w1[(4 * i4 + 0) * 32 + j] + a1 * w1[(4 * i4 + 1) * 32 + j] +
               a2 * w1[(4 * i4 + 2) * 32 + j] + a3 * w1[(4 * i4 + 3) * 32 + j];
    }
  }
  float z2[16];
#pragma unroll
  for (int j = 0; j < 16; ++j) z2[j] = b2s[j];
  for (int i = 0; i < 32; ++i) {
    float a = fmaxf(z1[i], 0.f);
#pragma unroll
    for (int j = 0; j < 16; ++j) z2[j] += a * w2[i * 16 + j];
  }
  float z3[8];
#pragma unroll
  for (int j = 0; j < 8; ++j) z3[j] = b3s[j];
  for (int i = 0; i < 16; ++i) {
    float a = fmaxf(z2[i], 0.f);
#pragma unroll
    for (int j = 0; j < 8; ++j) z3[j] += a * w3[i * 8 + j];
  }
  float z4[4];
#pragma unroll
  for (int j = 0; j < 4; ++j) z4[j] = b4s[j];
  for (int i = 0; i < 8; ++i) {
    float a = fmaxf(z3[i], 0.f);
#pragma unroll
    for (int j = 0; j < 4; ++j) z4[j] += a * w4[i * 4 + j];
  }
  float zo = obv;
#pragma unroll
  for (int i = 0; i < 4; ++i) zo += fmaxf(z4[i], 0.f) * wos[i];
  out[n] = 1.f / (1.f + __expf(-zo));
}

extern "C" void kernel_launch(void* const* d_in, const int* in_sizes, int n_in,
                              void* d_out, int out_size, void* d_ws, size_t ws_size,
                              hipStream_t stream) {
  const float* x  = (const float*)d_in[0];
  const int*   ei = (const int*)d_in[1];
  const float* W1 = (const float*)d_in[2];  const float* u1 = (const float*)d_in[3];
  const float* c1 = (const float*)d_in[4];  const float* b1 = (const float*)d_in[5];
  const float* W2 = (const float*)d_in[6];  const float* u2 = (const float*)d_in[7];
  const float* c2 = (const float*)d_in[8];  const float* b2 = (const float*)d_in[9];
  const float* W3 = (const float*)d_in[10]; const float* u3 = (const float*)d_in[11];
  const float* c3 = (const float*)d_in[12]; const float* b3 = (const float*)d_in[13];
  const float* gamma = (const float*)d_in[14]; const float* beta = (const float*)d_in[15];
  const float* lw1 = (const float*)d_in[16]; const float* lb1 = (const float*)d_in[17];
  const float* lw2 = (const float*)d_in[18]; const float* lb2 = (const float*)d_in[19];
  const float* lw3 = (const float*)d_in[20]; const float* lb3 = (const float*)d_in[21];
  const float* lw4 = (const float*)d_in[22]; const float* lb4 = (const float*)d_in[23];
  const float* ow  = (const float*)d_in[24]; const float* ob  = (const float*)d_in[25];
  float* out = (float*)d_out;

  u16*   tB   = (u16*)d_ws;                            // N*64 bf16  (N*32 f)
  u16*   h1B  = tB + (size_t)NNODES * 64;              // N*16 bf16  (N*8 f)
  u16*   h2B  = h1B + (size_t)NNODES * 16;             // N*32 bf16  (N*16 f)
  float* hA3  = (float*)d_ws + (size_t)NNODES * 56;    // N*64 fp32 (after 32+8+16)
  float* sA   = hA3 + (size_t)NNODES * 64;             // N*4  (s1, then s3)
  float* sB   = sA + (size_t)NNODES * 4;               // N*4  (s2)
  float* sums = sB + (size_t)NNODES * 4;               // 128
  float* Wk1  = sums + 128;                            // 4096
  float* Wk2  = Wk1 + 4096;                            // 2048
  float* Wk3  = Wk2 + 2048;                            // 8192
  int*   rowptr   = (int*)(Wk3 + 8192);                // N+1 (pad 8)
  int*   counts   = rowptr + NNODES + 8;               // N
  int*   blockSum = counts + NNODES;                   // 256
  u16*   col      = (u16*)(blockSum + 256);            // E u16
  u16*   rank     = col + NEDGES;                      // E u16

  hipMemsetAsync(counts, 0, NNODES * sizeof(int), stream);

  // ---- CSR by dst + W transposes (merged) ----
  histprep_kernel<<<(NEDGES + 255) / 256, 256, 0, stream>>>(ei, counts, rank,
                                                            W1, W2, W3, Wk1, Wk2, Wk3);
  scanA_kernel<<<SCAN_BLOCKS, 256, 0, stream>>>(counts, rowptr, blockSum, sums);
  scanBC_kernel<<<SCAN_BLOCKS, 256, 0, stream>>>(blockSum, rowptr);
  scatter_kernel<<<NSLICE * 8, 256, 0, stream>>>(ei, rowptr, rank, col);

  // ---- layer 1: 64 -> 16 (t-GEMM + s1 fused; gather + s2 fused, bf16 h1) ----
  ngemm1_kernel<<<(NNODES + 63) / 64, 256, 0, stream>>>(x, Wk1, u1, tB, sA);
  gather1_kernel<<<(NNODES + 31) / 32, 256, 0, stream>>>(rowptr, col, sA, tB, c1, b1,
                                                         u2, h1B, sB);

  // ---- layer 2: 16 -> 32 (fused gather+transform; bf16 in, bf16 out) ----
  fusedG_kernel<16, 32, 16, true, true><<<(NNODES + 127) / 128, 256, 0, stream>>>(
      rowptr, col, sB, h1B, Wk2, c2, b2, h2B);

  // ---- layer 3: 32 -> 64 (fused gather+transform; bf16 in, fp32 out) ----
  s_kernel_bf<32><<<(NNODES * 4 + 255) / 256, 256, 0, stream>>>(h2B, u3, sA);
  fusedG_kernel<32, 64, 16, true, false><<<(NNODES + 63) / 64, 256, 0, stream>>>(
      rowptr, col, sA, h2B, Wk3, c3, b3, hA3);

  // ---- BN stats + MLP head ----
  stats_kernel<<<256, 256, 0, stream>>>(hA3, sums);
  mlp_kernel<<<(NNODES + 255) / 256, 256, 0, stream>>>(hA3, sums, gamma, beta, lw1, lb1,
                                                       lw2, lb2, lw3, lb3, lw4, lb4,
                                                       ow, ob, out);
}